// Round 15
// baseline (327.748 us; speedup 1.0000x reference)
//
#include <hip/hip_runtime.h>
#include <cstdint>

typedef unsigned int u32;
typedef unsigned long long u64;

#define NCLS 21
#define TOPK 200
#define MAXP 8732
#define CAND 384
#define NXCD 8

// Scores: XLA:GPU(gfx950) softmax emulation — exp(x) = v_exp_f32(x*log2e),
// butterfly-tree sum. Everything else stepwise IEEE f32, no fusion.
// ALL numeric ops bit-identical to the round-13/14 passing kernels.
#pragma clang fp contract(off)

__device__ __forceinline__ float tri_expf(float x) {
  float t = __fmul_rn(x, 1.4426950408889634f);
  return __builtin_amdgcn_exp2f(t);               // v_exp_f32
}

__device__ __forceinline__ float butterfly_sum21(const float* e) {
  float v[32];
#pragma unroll
  for (int k = 0; k < NCLS; ++k) v[k] = e[k];
#pragma unroll
  for (int k = NCLS; k < 32; ++k) v[k] = 0.0f;
  float a[16], b[8], c4[4], d2[2];
#pragma unroll
  for (int i = 0; i < 16; ++i) a[i] = __fadd_rn(v[i], v[i + 16]);
#pragma unroll
  for (int i = 0; i < 8; ++i) b[i] = __fadd_rn(a[i], a[i + 8]);
#pragma unroll
  for (int i = 0; i < 4; ++i) c4[i] = __fadd_rn(b[i], b[i + 4]);
#pragma unroll
  for (int i = 0; i < 2; ++i) d2[i] = __fadd_rn(c4[i], c4[i + 2]);
  return __fadd_rn(d2[0], d2[1]);
}

__device__ __forceinline__ void softmax_row(const float* __restrict__ row,
                                            float* e, float& mx, float& S) {
  float xs[NCLS];
#pragma unroll
  for (int k = 0; k < NCLS; ++k) xs[k] = row[k];
  mx = xs[0];
#pragma unroll
  for (int k = 1; k < NCLS; ++k) mx = fmaxf(mx, xs[k]);
#pragma unroll
  for (int k = 0; k < NCLS; ++k) e[k] = tri_expf(__fsub_rn(xs[k], mx));
  S = butterfly_sum21(e);
}

__device__ __forceinline__ int swz_task(int bid, int nwg) {
  if ((nwg % NXCD) == 0) return (bid % NXCD) * (nwg / NXCD) + bid / NXCD;
  return bid;
}

// ---------------- prep TIER2: transposed f32 probs (coalesced write per class)
__global__ __launch_bounds__(256) void prep2_k(const float* __restrict__ conf,
                                               float* __restrict__ probs_t,
                                               int B, int P) {
  int gid = blockIdx.x * 256 + threadIdx.x;
  if (gid >= B * P) return;
  int b = gid / P, p = gid - b * P;
  float e[NCLS], mx, S;
  softmax_row(conf + (size_t)gid * NCLS, e, mx, S);
#pragma unroll
  for (int c = 1; c < NCLS; ++c)
    probs_t[((size_t)b * (NCLS - 1) + (c - 1)) * P + p] = __fdiv_rn(e[c], S);
}

// ---------------- prep TIER1: per-(b,p) denoms (mx, S)
__global__ __launch_bounds__(256) void prep1_k(const float* __restrict__ conf,
                                               float2* __restrict__ denoms, int BP) {
  int gid = blockIdx.x * 256 + threadIdx.x;
  if (gid >= BP) return;
  float e[NCLS], mx, S;
  softmax_row(conf + (size_t)gid * NCLS, e, mx, S);
  denoms[gid] = make_float2(mx, S);
}

// ---------------- select: radix top-200 -> ordered keys
// TIER 2: coalesced probs_t read; 1: denoms + conf gather; 0: full recompute
template<int TIER>
__global__ __launch_bounds__(256) void sel_k(const float* __restrict__ conf,
                                             const float2* __restrict__ denoms,
                                             const float* __restrict__ probs_t,
                                             u64* __restrict__ keys, int B, int P) {
  __shared__ __align__(16) u32 sc[MAXP];
  __shared__ u64 ckey[CAND];
  __shared__ u32 hist[256];
  __shared__ int srt[TOPK];
  __shared__ u32 s_prefix;
  __shared__ int s_K, s_cnt;

  const int tid = threadIdx.x;
  const int task = swz_task(blockIdx.x, gridDim.x);
  const int b = task / (NCLS - 1), cm1 = task - b * (NCLS - 1);
  const int c = cm1 + 1;

  // ---- Phase A: f32 prob bits into LDS (values bit-identical across tiers)
  if (TIER == 2) {
    const float* base = probs_t + (size_t)task * P;
    for (int p = tid; p < P; p += 256) sc[p] = __float_as_uint(base[p]);
  } else if (TIER == 1) {
    for (int p = tid; p < P; p += 256) {
      float2 d = denoms[(size_t)b * P + p];
      float cv = conf[((size_t)b * P + p) * NCLS + c];
      float v = __fdiv_rn(tri_expf(__fsub_rn(cv, d.x)), d.y);
      sc[p] = __float_as_uint(v);
    }
  } else {
    for (int p = tid; p < P; p += 256) {
      float e[NCLS], mx, S;
      softmax_row(conf + ((size_t)b * P + p) * NCLS, e, mx, S);
      sc[p] = __float_as_uint(__fdiv_rn(e[c], S));
    }
  }
  if (tid == 0) s_cnt = 0;
  __syncthreads();

  // ---- Phase B: radix-select rank-200 threshold T (exact, with ties)
  u32 prefix = 0; int K = TOPK;
  for (int pass = 0; pass < 4; ++pass) {
    int shift = 24 - 8 * pass;
    u32 known = (pass == 0) ? 0u : (0xFFFFFFFFu << (32 - 8 * pass));
    hist[tid] = 0;
    __syncthreads();
    // ballot-aggregated histogram: one atomic per same-digit lane-group
    for (int p = tid; p < P; p += 256) {
      u32 v = sc[p];
      bool act = ((v & known) == prefix);
      u32 d = (v >> shift) & 0xFFu;
      u64 m = __ballot((int)act);
#pragma unroll
      for (int bit = 0; bit < 8; ++bit) {
        u64 vb = __ballot((int)((d >> bit) & 1u));
        m &= ((d >> bit) & 1u) ? vb : ~vb;
      }
      if (act) {
        int lane = (int)(tid & 63);
        int leader = __ffsll((long long)m) - 1;
        if (lane == leader) atomicAdd(&hist[d], (u32)__popcll(m));
      }
    }
    __syncthreads();
    // single-wave suffix scan: hist[t] = count(digit >= t)
    if (tid < 64) {
      int l = tid;
      u32 c0 = hist[4 * l], c1 = hist[4 * l + 1], c2 = hist[4 * l + 2], c3 = hist[4 * l + 3];
      u32 s3 = c3, s2 = c2 + s3, s1 = c1 + s2, s0 = c0 + s1;
      u32 tot = s0, acc = tot;
#pragma unroll
      for (int off = 1; off < 64; off <<= 1) {
        u32 o = __shfl_down(acc, off);
        if (l + off < 64) acc += o;
      }
      u32 upper = acc - tot;   // sum of totals for lanes > l
      hist[4 * l]     = s0 + upper;
      hist[4 * l + 1] = s1 + upper;
      hist[4 * l + 2] = s2 + upper;
      hist[4 * l + 3] = s3 + upper;
    }
    __syncthreads();
    u32 ge = hist[tid];
    u32 gt = (tid == 255) ? 0u : hist[tid + 1];
    if (ge >= (u32)K && gt < (u32)K) { s_prefix = prefix | ((u32)tid << shift); s_K = K - (int)gt; }
    __syncthreads();
    prefix = s_prefix; K = s_K;
    __syncthreads();
  }
  const u32 T = prefix;

  // ---- Phase C: compact candidates (bits >= T)
  for (int p = tid; p < P; p += 256) {
    u32 v = sc[p];
    if (v >= T) {
      int slot = atomicAdd(&s_cnt, 1);
      if (slot < CAND)
        ckey[slot] = ((u64)v << 32) | (u64)(0xFFFFFFFFu - (u32)p);
    }
  }
  __syncthreads();
  int cnt = s_cnt; if (cnt > CAND) cnt = CAND;

  // ---- Phase D: exact rank by counting
  for (int i = tid; i < cnt; i += 256) {
    u64 k = ckey[i]; int r = 0;
    for (int j = 0; j < cnt; ++j) r += (ckey[j] > k) ? 1 : 0;
    if (r < TOPK) srt[r] = i;
  }
  __syncthreads();
  if (tid < TOPK) keys[(size_t)task * TOPK + tid] = ckey[srt[tid]];
}

// ---------------- nms: 256 thr; parallel IoU mask matrix + scalar mask scan
__global__ __launch_bounds__(256) void nms_k(const float* __restrict__ loc,
                                             const float* __restrict__ priors,
                                             const u64* __restrict__ keys,
                                             float* __restrict__ out, int B, int P) {
  __shared__ __align__(16) float bx[TOPK][4];
  __shared__ float vals[TOPK];
  __shared__ u64 msk[TOPK][4];
  __shared__ __align__(16) float st[TOPK * 5];
  __shared__ int s_nv;

  const int tid = threadIdx.x;
  const int task = swz_task(blockIdx.x, gridDim.x);
  const int b = task / (NCLS - 1), cm1 = task - b * (NCLS - 1);

  if (cm1 == 0) {   // zero the background-class rows of this image
    float* bg = out + (size_t)b * (NCLS * TOPK * 5);
    for (int i = tid; i < TOPK * 5; i += 256) bg[i] = 0.0f;
  }
  if (tid == 0) s_nv = TOPK;
  __syncthreads();

  // decode (bit-identical op sequence)
  if (tid < TOPK) {
    u64 key = keys[(size_t)task * TOPK + tid];
    float v = __uint_as_float((u32)(key >> 32));
    int p = (int)(0xFFFFFFFFu - (u32)(key & 0xFFFFFFFFull));
    float4 lp = ((const float4*)loc)[(size_t)b * P + p];
    float4 pr = ((const float4*)priors)[p];
    float tx = __fmul_rn(__fmul_rn(lp.x, 0.1f), pr.z);
    float ty = __fmul_rn(__fmul_rn(lp.y, 0.1f), pr.w);
    float cx = __fadd_rn(pr.x, tx);
    float cy = __fadd_rn(pr.y, ty);
    float w = __fmul_rn(pr.z, expf(__fmul_rn(lp.z, 0.2f)));
    float h = __fmul_rn(pr.w, expf(__fmul_rn(lp.w, 0.2f)));
    float hw = __fmul_rn(w, 0.5f), hh = __fmul_rn(h, 0.5f);
    bx[tid][0] = __fsub_rn(cx, hw);
    bx[tid][1] = __fsub_rn(cy, hh);
    bx[tid][2] = __fadd_rn(cx, hw);
    bx[tid][3] = __fadd_rn(cy, hh);
    vals[tid] = v;
    if (!(v > 0.01f)) atomicMin(&s_nv, tid);
  }
  __syncthreads();
  const int n = s_nv;

  // parallel IoU mask matrix: row r (thread r < n), uniform j loop (broadcast)
  if (tid < n) {
    float rx1 = bx[tid][0], ry1 = bx[tid][1], rx2 = bx[tid][2], ry2 = bx[tid][3];
    float ar = __fmul_rn(__fsub_rn(rx2, rx1), __fsub_rn(ry2, ry1));
    u64 m0 = 0, m1 = 0, m2 = 0, m3 = 0;
    for (int j = 0; j < n; ++j) {
      float jx1 = bx[j][0], jy1 = bx[j][1], jx2 = bx[j][2], jy2 = bx[j][3];
      float aj = __fmul_rn(__fsub_rn(jx2, jx1), __fsub_rn(jy2, jy1));
      float ww = fmaxf(__fsub_rn(fminf(rx2, jx2), fmaxf(rx1, jx1)), 0.0f);
      float hh = fmaxf(__fsub_rn(fminf(ry2, jy2), fmaxf(ry1, jy1)), 0.0f);
      float inter = __fmul_rn(ww, hh);
      float den = __fsub_rn(__fadd_rn(ar, aj), inter);
      float iou = __fdiv_rn(inter, den);   // NaN (0/0) -> comparison false
      if (iou > 0.45f) {
        u64 bit = 1ull << (j & 63);
        int w4 = j >> 6;
        if (w4 == 0) m0 |= bit; else if (w4 == 1) m1 |= bit;
        else if (w4 == 2) m2 |= bit; else m3 |= bit;
      }
    }
    msk[tid][0] = m0; msk[tid][1] = m1; msk[tid][2] = m2; msk[tid][3] = m3;
  }
  __syncthreads();

  // zero staging + redundant scalar greedy scan (all threads, uniform)
  for (int i = tid; i < TOPK * 5; i += 256) st[i] = 0.0f;
  u64 remv0 = 0, remv1 = 0, remv2 = 0, remv3 = 0;
  u64 kp0 = 0, kp1 = 0, kp2 = 0, kp3 = 0;
  {
    int i = 0;
#define SCAN_WORD(KW, RW)                                              \
    for (int bpos = 0; bpos < 64 && i < n; ++bpos, ++i) {              \
      if (!((RW >> bpos) & 1ull)) {                                    \
        KW |= 1ull << bpos;                                            \
        remv0 |= msk[i][0]; remv1 |= msk[i][1];                        \
        remv2 |= msk[i][2]; remv3 |= msk[i][3];                        \
      }                                                                \
    }
    SCAN_WORD(kp0, remv0)
    SCAN_WORD(kp1, remv1)
    SCAN_WORD(kp2, remv2)
    SCAN_WORD(kp3, remv3)
#undef SCAN_WORD
  }
  __syncthreads();

  // compaction: kept rows to front
  if (tid < TOPK) {
    int w4 = tid >> 6, bpos = tid & 63;
    u64 kw = (w4 == 0) ? kp0 : (w4 == 1) ? kp1 : (w4 == 2) ? kp2 : kp3;
    if ((kw >> bpos) & 1ull) {
      int pos = (int)__popcll(kw & ((1ull << bpos) - 1ull));
      if (w4 > 0) pos += (int)__popcll(kp0);
      if (w4 > 1) pos += (int)__popcll(kp1);
      if (w4 > 2) pos += (int)__popcll(kp2);
      st[pos * 5 + 0] = vals[tid];
      st[pos * 5 + 1] = bx[tid][0];
      st[pos * 5 + 2] = bx[tid][1];
      st[pos * 5 + 3] = bx[tid][2];
      st[pos * 5 + 4] = bx[tid][3];
    }
  }
  __syncthreads();
  float* op = out + (size_t)(b * NCLS + 1 + cm1) * (TOPK * 5);
  if (tid < TOPK * 5 / 4) ((float4*)op)[tid] = ((const float4*)st)[tid];
}

// ---------------- fused fallback (verified R13 kernel), used if ws tiny
__global__ __launch_bounds__(256) void fused_k(
    const float* __restrict__ loc, const float* __restrict__ conf,
    const float* __restrict__ priors, float* __restrict__ out, int B, int P) {
  __shared__ __align__(16) u32 sc[MAXP];
  __shared__ u64 ckey[CAND];
  __shared__ u32 hist[256];
  __shared__ int srt[TOPK];
  __shared__ float bx[TOPK][4];
  __shared__ float vals[TOPK];
  __shared__ __align__(16) float st[TOPK * 5];
  __shared__ u32 s_prefix;
  __shared__ int s_K, s_cnt, s_nv;
  __shared__ u64 s_kw[4];

  const int tid = threadIdx.x;
  const int task = blockIdx.x;
  const int b = task / (NCLS - 1), cm1 = task - b * (NCLS - 1);
  const int c = cm1 + 1;

  if (cm1 == 0) {
    float* bg = out + (size_t)b * (NCLS * TOPK * 5);
    for (int i = tid; i < TOPK * 5; i += 256) bg[i] = 0.0f;
  }
  for (int p = tid; p < P; p += 256) {
    float e[NCLS], mx, S;
    softmax_row(conf + ((size_t)b * P + p) * NCLS, e, mx, S);
    sc[p] = __float_as_uint(__fdiv_rn(e[c], S));
  }
  if (tid == 0) s_cnt = 0;
  __syncthreads();
  u32 prefix = 0; int K = TOPK;
  for (int pass = 0; pass < 4; ++pass) {
    int shift = 24 - 8 * pass;
    u32 known = (pass == 0) ? 0u : (0xFFFFFFFFu << (32 - 8 * pass));
    hist[tid] = 0;
    __syncthreads();
    for (int p = tid; p < P; p += 256) {
      u32 v = sc[p];
      if ((v & known) == prefix) atomicAdd(&hist[(v >> shift) & 0xFFu], 1u);
    }
    __syncthreads();
    for (int off = 1; off < 256; off <<= 1) {
      u32 add = (tid + off < 256) ? hist[tid + off] : 0u;
      __syncthreads();
      hist[tid] += add;
      __syncthreads();
    }
    u32 ge = hist[tid];
    u32 gt = (tid == 255) ? 0u : hist[tid + 1];
    if (ge >= (u32)K && gt < (u32)K) { s_prefix = prefix | ((u32)tid << shift); s_K = K - (int)gt; }
    __syncthreads();
    prefix = s_prefix; K = s_K;
    __syncthreads();
  }
  const u32 T = prefix;
  for (int p = tid; p < P; p += 256) {
    u32 v = sc[p];
    if (v >= T) {
      int slot = atomicAdd(&s_cnt, 1);
      if (slot < CAND) ckey[slot] = ((u64)v << 32) | (u64)(0xFFFFFFFFu - (u32)p);
    }
  }
  __syncthreads();
  int cnt = s_cnt; if (cnt > CAND) cnt = CAND;
  for (int i = tid; i < cnt; i += 256) {
    u64 k = ckey[i]; int r = 0;
    for (int j = 0; j < cnt; ++j) r += (ckey[j] > k) ? 1 : 0;
    if (r < TOPK) srt[r] = i;
  }
  if (tid == 0) s_nv = TOPK;
  __syncthreads();
  if (tid < TOPK) {
    u64 key = ckey[srt[tid]];
    float v = __uint_as_float((u32)(key >> 32));
    int p = (int)(0xFFFFFFFFu - (u32)(key & 0xFFFFFFFFull));
    float4 lp = ((const float4*)loc)[(size_t)b * P + p];
    float4 pr = ((const float4*)priors)[p];
    float tx = __fmul_rn(__fmul_rn(lp.x, 0.1f), pr.z);
    float ty = __fmul_rn(__fmul_rn(lp.y, 0.1f), pr.w);
    float cx = __fadd_rn(pr.x, tx);
    float cy = __fadd_rn(pr.y, ty);
    float w = __fmul_rn(pr.z, expf(__fmul_rn(lp.z, 0.2f)));
    float h = __fmul_rn(pr.w, expf(__fmul_rn(lp.w, 0.2f)));
    float hw = __fmul_rn(w, 0.5f), hh = __fmul_rn(h, 0.5f);
    bx[tid][0] = __fsub_rn(cx, hw);
    bx[tid][1] = __fsub_rn(cy, hh);
    bx[tid][2] = __fadd_rn(cx, hw);
    bx[tid][3] = __fadd_rn(cy, hh);
    vals[tid] = v;
    if (!(v > 0.01f)) atomicMin(&s_nv, tid);
  }
  __syncthreads();
  if (tid < 64) {
    int lane = tid;
    float jx1[4], jy1[4], jx2[4], jy2[4], aj[4];
#pragma unroll
    for (int s = 0; s < 4; ++s) {
      int j = s * 64 + lane;
      if (j < TOPK) { jx1[s]=bx[j][0]; jy1[s]=bx[j][1]; jx2[s]=bx[j][2]; jy2[s]=bx[j][3]; }
      else { jx1[s]=0.f; jy1[s]=0.f; jx2[s]=0.f; jy2[s]=0.f; }
      aj[s] = __fmul_rn(__fsub_rn(jx2[s], jx1[s]), __fsub_rn(jy2[s], jy1[s]));
    }
    u32 keepn = 0;
    int n = s_nv;
    for (int i = 0; i < n; ++i) {
      float ix1 = bx[i][0], iy1 = bx[i][1], ix2 = bx[i][2], iy2 = bx[i][3];
      float ai = __fmul_rn(__fsub_rn(ix2, ix1), __fsub_rn(iy2, iy1));
      bool sup = false;
#pragma unroll
      for (int s = 0; s < 4; ++s) {
        float ww = fmaxf(__fsub_rn(fminf(ix2, jx2[s]), fmaxf(ix1, jx1[s])), 0.0f);
        float hh = fmaxf(__fsub_rn(fminf(iy2, jy2[s]), fmaxf(iy1, jy1[s])), 0.0f);
        float inter = __fmul_rn(ww, hh);
        float den = __fsub_rn(__fadd_rn(ai, aj[s]), inter);
        float iou = __fdiv_rn(inter, den);
        if (((keepn >> s) & 1u) && (iou > 0.45f)) sup = true;
      }
      if (!__any((int)sup)) { if (lane == (i & 63)) keepn |= 1u << (i >> 6); }
    }
    u64 w0 = __ballot((int)(keepn & 1u));
    u64 w1 = __ballot((int)((keepn >> 1) & 1u));
    u64 w2 = __ballot((int)((keepn >> 2) & 1u));
    u64 w3 = __ballot((int)((keepn >> 3) & 1u));
    if (lane == 0) { s_kw[0]=w0; s_kw[1]=w1; s_kw[2]=w2; s_kw[3]=w3; }
  }
  __syncthreads();
  for (int i = tid; i < TOPK * 5; i += 256) st[i] = 0.0f;
  __syncthreads();
  if (tid < TOPK) {
    int w = tid >> 6, bit = tid & 63;
    u64 kwv = s_kw[w];
    if ((kwv >> bit) & 1ull) {
      int pos = (int)__popcll(kwv & ((1ull << bit) - 1ull));
      for (int w2 = 0; w2 < w; ++w2) pos += (int)__popcll(s_kw[w2]);
      st[pos*5+0] = vals[tid];
      st[pos*5+1] = bx[tid][0];
      st[pos*5+2] = bx[tid][1];
      st[pos*5+3] = bx[tid][2];
      st[pos*5+4] = bx[tid][3];
    }
  }
  __syncthreads();
  float* op = out + (size_t)(b * NCLS + 1 + cm1) * (TOPK * 5);
  if (tid < TOPK * 5 / 4) ((float4*)op)[tid] = ((const float4*)st)[tid];
}

extern "C" void kernel_launch(void* const* d_in, const int* in_sizes, int n_in,
                              void* d_out, int out_size, void* d_ws, size_t ws_size,
                              hipStream_t stream) {
  const float* loc    = (const float*)d_in[0];
  const float* conf   = (const float*)d_in[1];
  const float* priors = (const float*)d_in[2];
  float* out = (float*)d_out;

  int P = in_sizes[2] / 4;              // 8732
  int B = in_sizes[0] / (P * 4);        // 128
  int tasks = B * (NCLS - 1);           // 2560
  int BP = B * P;

  size_t keysB = (size_t)tasks * TOPK * sizeof(u64);            // ~4.1 MB
  size_t probB = (size_t)B * (NCLS - 1) * P * sizeof(float);    // ~89.4 MB
  size_t denB  = (size_t)BP * sizeof(float2);                   // ~8.9 MB

  if (ws_size >= probB + keysB) {
    float* probs_t = (float*)d_ws;
    u64* keys = (u64*)((char*)d_ws + probB);
    prep2_k<<<(BP + 255) / 256, 256, 0, stream>>>(conf, probs_t, B, P);
    sel_k<2><<<tasks, 256, 0, stream>>>(conf, nullptr, probs_t, keys, B, P);
    nms_k<<<tasks, 256, 0, stream>>>(loc, priors, keys, out, B, P);
  } else if (ws_size >= denB + keysB) {
    float2* denoms = (float2*)d_ws;
    u64* keys = (u64*)((char*)d_ws + denB);
    prep1_k<<<(BP + 255) / 256, 256, 0, stream>>>(conf, denoms, BP);
    sel_k<1><<<tasks, 256, 0, stream>>>(conf, denoms, nullptr, keys, B, P);
    nms_k<<<tasks, 256, 0, stream>>>(loc, priors, keys, out, B, P);
  } else if (ws_size >= keysB) {
    u64* keys = (u64*)d_ws;
    sel_k<0><<<tasks, 256, 0, stream>>>(conf, nullptr, nullptr, keys, B, P);
    nms_k<<<tasks, 256, 0, stream>>>(loc, priors, keys, out, B, P);
  } else {
    fused_k<<<tasks, 256, 0, stream>>>(loc, conf, priors, out, B, P);
  }
}

// Round 16
// 277.376 us; speedup vs baseline: 1.1816x; 1.1816x over previous
//
#include <hip/hip_runtime.h>
#include <cstdint>

typedef unsigned int u32;
typedef unsigned long long u64;

#define NCLS 21
#define TOPK 200
#define MAXP 8732
#define CAND 384
#define NXCD 8

// Scores: XLA:GPU(gfx950) softmax emulation — exp(x) = v_exp_f32(x*log2e),
// butterfly-tree sum. Everything else stepwise IEEE f32, no fusion.
// ALL numeric values bit-identical to the round-13/14/15 passing kernels.
#pragma clang fp contract(off)

__device__ __forceinline__ float tri_expf(float x) {
  float t = __fmul_rn(x, 1.4426950408889634f);
  return __builtin_amdgcn_exp2f(t);               // v_exp_f32
}

__device__ __forceinline__ float butterfly_sum21(const float* e) {
  float v[32];
#pragma unroll
  for (int k = 0; k < NCLS; ++k) v[k] = e[k];
#pragma unroll
  for (int k = NCLS; k < 32; ++k) v[k] = 0.0f;
  float a[16], b[8], c4[4], d2[2];
#pragma unroll
  for (int i = 0; i < 16; ++i) a[i] = __fadd_rn(v[i], v[i + 16]);
#pragma unroll
  for (int i = 0; i < 8; ++i) b[i] = __fadd_rn(a[i], a[i + 8]);
#pragma unroll
  for (int i = 0; i < 4; ++i) c4[i] = __fadd_rn(b[i], b[i + 4]);
#pragma unroll
  for (int i = 0; i < 2; ++i) d2[i] = __fadd_rn(c4[i], c4[i + 2]);
  return __fadd_rn(d2[0], d2[1]);
}

__device__ __forceinline__ void softmax_row(const float* __restrict__ row,
                                            float* e, float& mx, float& S) {
  float xs[NCLS];
#pragma unroll
  for (int k = 0; k < NCLS; ++k) xs[k] = row[k];
  mx = xs[0];
#pragma unroll
  for (int k = 1; k < NCLS; ++k) mx = fmaxf(mx, xs[k]);
#pragma unroll
  for (int k = 0; k < NCLS; ++k) e[k] = tri_expf(__fsub_rn(xs[k], mx));
  S = butterfly_sum21(e);
}

__device__ __forceinline__ int swz_task(int bid, int nwg) {
  if ((nwg % NXCD) == 0) return (bid % NXCD) * (nwg / NXCD) + bid / NXCD;
  return bid;
}

// ---------------- prep2: transposed f32 probs.
// Division via f64 reciprocal-multiply: bit-identical to __fdiv_rn(e,S) for
// all normal f32 (no halfway cases exist for f32/f32; separation >= 2^-48 rel,
// f64 path error <= 2^-52). Data range (logits ~ +-10) keeps q normal.
__global__ __launch_bounds__(256) void prep2_k(const float* __restrict__ conf,
                                               float* __restrict__ probs_t,
                                               int B, int P) {
  int gid = blockIdx.x * 256 + threadIdx.x;
  if (gid >= B * P) return;
  int b = gid / P, p = gid - b * P;
  float e[NCLS], mx, S;
  softmax_row(conf + (size_t)gid * NCLS, e, mx, S);
  double invS = 1.0 / (double)S;
#pragma unroll
  for (int c = 1; c < NCLS; ++c)
    probs_t[((size_t)b * (NCLS - 1) + (c - 1)) * P + p] =
        (float)((double)e[c] * invS);
}

// ---------------- fused select + NMS (TIER2: reads probs_t)
__global__ __launch_bounds__(256) void fused2_k(const float* __restrict__ loc,
                                                const float* __restrict__ priors,
                                                const float* __restrict__ probs_t,
                                                float* __restrict__ out, int B, int P) {
  __shared__ __align__(16) u32 sc[MAXP];
  __shared__ u64 ckey[CAND];
  __shared__ u32 hist[256];
  __shared__ int srt[TOPK];
  __shared__ u32 s_prefix;
  __shared__ int s_K, s_cnt, s_nv;

  // overlays on sc (dead after Phase C/D)
  float (*bx)[4] = (float (*)[4])sc;         // bytes [0,3200)
  float* vals = (float*)(sc + 800);          // bytes [3200,4000)
  u64 (*msk)[4] = (u64 (*)[4])(sc + 1000);   // bytes [4000,10400)
  float* st = (float*)(sc + 2600);           // bytes [10400,14400)

  const int tid = threadIdx.x;
  const int task = swz_task(blockIdx.x, gridDim.x);
  const int b = task / (NCLS - 1), cm1 = task - b * (NCLS - 1);

  if (cm1 == 0) {   // zero the background-class rows of this image
    float* bg = out + (size_t)b * (NCLS * TOPK * 5);
    for (int i = tid; i < TOPK * 5; i += 256) bg[i] = 0.0f;
  }
  hist[tid] = 0;
  if (tid == 0) { s_cnt = 0; s_nv = TOPK; }
  __syncthreads();

  // ---- Phase A + radix pass 0 histogram (folded)
  {
    const float* base = probs_t + (size_t)task * P;
    for (int p = tid; p < P; p += 256) {
      u32 v = __float_as_uint(base[p]);
      sc[p] = v;
      atomicAdd(&hist[v >> 24], 1u);
    }
  }
  __syncthreads();

  u32 prefix = 0; int K = TOPK;
  // ---- radix passes: pass 0 uses the folded histogram; passes 1-3 rescan
  for (int pass = 0; pass < 4; ++pass) {
    int shift = 24 - 8 * pass;
    if (pass > 0) {
      u32 known = 0xFFFFFFFFu << (32 - 8 * pass);
      hist[tid] = 0;
      __syncthreads();
      for (int p = tid; p < P; p += 256) {
        u32 v = sc[p];
        if ((v & known) == prefix) atomicAdd(&hist[(v >> shift) & 0xFFu], 1u);
      }
      __syncthreads();
    }
    // single-wave suffix scan: hist[t] = count(digit >= t)
    if (tid < 64) {
      int l = tid;
      u32 c0 = hist[4 * l], c1 = hist[4 * l + 1], c2 = hist[4 * l + 2], c3 = hist[4 * l + 3];
      u32 s3 = c3, s2 = c2 + s3, s1 = c1 + s2, s0 = c0 + s1;
      u32 tot = s0, acc = tot;
#pragma unroll
      for (int off = 1; off < 64; off <<= 1) {
        u32 o = __shfl_down(acc, off);
        if (l + off < 64) acc += o;
      }
      u32 upper = acc - tot;   // sum of totals for lanes > l
      hist[4 * l]     = s0 + upper;
      hist[4 * l + 1] = s1 + upper;
      hist[4 * l + 2] = s2 + upper;
      hist[4 * l + 3] = s3 + upper;
    }
    __syncthreads();
    u32 ge = hist[tid];
    u32 gt = (tid == 255) ? 0u : hist[tid + 1];
    if (ge >= (u32)K && gt < (u32)K) { s_prefix = prefix | ((u32)tid << shift); s_K = K - (int)gt; }
    __syncthreads();
    prefix = s_prefix; K = s_K;
    __syncthreads();
  }
  const u32 T = prefix;

  // ---- Phase C: compact candidates (bits >= T)
  for (int p = tid; p < P; p += 256) {
    u32 v = sc[p];
    if (v >= T) {
      int slot = atomicAdd(&s_cnt, 1);
      if (slot < CAND)
        ckey[slot] = ((u64)v << 32) | (u64)(0xFFFFFFFFu - (u32)p);
    }
  }
  __syncthreads();
  int cnt = s_cnt; if (cnt > CAND) cnt = CAND;

  // ---- Phase D: exact rank by counting
  for (int i = tid; i < cnt; i += 256) {
    u64 k = ckey[i]; int r = 0;
    for (int j = 0; j < cnt; ++j) r += (ckey[j] > k) ? 1 : 0;
    if (r < TOPK) srt[r] = i;
  }
  __syncthreads();   // sc dead from here; overlays become live

  // ---- decode top-200 (bit-identical op sequence)
  if (tid < TOPK) {
    u64 key = ckey[srt[tid]];
    float v = __uint_as_float((u32)(key >> 32));
    int p = (int)(0xFFFFFFFFu - (u32)(key & 0xFFFFFFFFull));
    float4 lp = ((const float4*)loc)[(size_t)b * P + p];
    float4 pr = ((const float4*)priors)[p];
    float tx = __fmul_rn(__fmul_rn(lp.x, 0.1f), pr.z);
    float ty = __fmul_rn(__fmul_rn(lp.y, 0.1f), pr.w);
    float cx = __fadd_rn(pr.x, tx);
    float cy = __fadd_rn(pr.y, ty);
    float w = __fmul_rn(pr.z, expf(__fmul_rn(lp.z, 0.2f)));
    float h = __fmul_rn(pr.w, expf(__fmul_rn(lp.w, 0.2f)));
    float hw = __fmul_rn(w, 0.5f), hh = __fmul_rn(h, 0.5f);
    bx[tid][0] = __fsub_rn(cx, hw);
    bx[tid][1] = __fsub_rn(cy, hh);
    bx[tid][2] = __fadd_rn(cx, hw);
    bx[tid][3] = __fadd_rn(cy, hh);
    vals[tid] = v;
    if (!(v > 0.01f)) atomicMin(&s_nv, tid);
  }
  __syncthreads();
  const int n = s_nv;

  // ---- parallel IoU mask matrix (row per thread, uniform broadcast j loop)
  if (tid < n) {
    float rx1 = bx[tid][0], ry1 = bx[tid][1], rx2 = bx[tid][2], ry2 = bx[tid][3];
    float ar = __fmul_rn(__fsub_rn(rx2, rx1), __fsub_rn(ry2, ry1));
    u64 m0 = 0, m1 = 0, m2 = 0, m3 = 0;
    for (int j = 0; j < n; ++j) {
      float jx1 = bx[j][0], jy1 = bx[j][1], jx2 = bx[j][2], jy2 = bx[j][3];
      float aj = __fmul_rn(__fsub_rn(jx2, jx1), __fsub_rn(jy2, jy1));
      float ww = fmaxf(__fsub_rn(fminf(rx2, jx2), fmaxf(rx1, jx1)), 0.0f);
      float hh = fmaxf(__fsub_rn(fminf(ry2, jy2), fmaxf(ry1, jy1)), 0.0f);
      float inter = __fmul_rn(ww, hh);
      float den = __fsub_rn(__fadd_rn(ar, aj), inter);
      float iou = __fdiv_rn(inter, den);   // NaN (0/0) -> comparison false
      if (iou > 0.45f) {
        u64 bit = 1ull << (j & 63);
        int w4 = j >> 6;
        if (w4 == 0) m0 |= bit; else if (w4 == 1) m1 |= bit;
        else if (w4 == 2) m2 |= bit; else m3 |= bit;
      }
    }
    msk[tid][0] = m0; msk[tid][1] = m1; msk[tid][2] = m2; msk[tid][3] = m3;
  }
  __syncthreads();

  // ---- redundant scalar greedy scan (uniform across threads)
  u64 remv0 = 0, remv1 = 0, remv2 = 0, remv3 = 0;
  u64 kp0 = 0, kp1 = 0, kp2 = 0, kp3 = 0;
  {
    int i = 0;
#define SCAN_WORD(KW, RW)                                              \
    for (int bpos = 0; bpos < 64 && i < n; ++bpos, ++i) {              \
      if (!((RW >> bpos) & 1ull)) {                                    \
        KW |= 1ull << bpos;                                            \
        remv0 |= msk[i][0]; remv1 |= msk[i][1];                        \
        remv2 |= msk[i][2]; remv3 |= msk[i][3];                        \
      }                                                                \
    }
    SCAN_WORD(kp0, remv0)
    SCAN_WORD(kp1, remv1)
    SCAN_WORD(kp2, remv2)
    SCAN_WORD(kp3, remv3)
#undef SCAN_WORD
  }
  __syncthreads();   // msk reads done before st (overlap-safe: disjoint anyway)

  for (int i = tid; i < TOPK * 5; i += 256) st[i] = 0.0f;
  __syncthreads();
  if (tid < TOPK) {
    int w4 = tid >> 6, bpos = tid & 63;
    u64 kw = (w4 == 0) ? kp0 : (w4 == 1) ? kp1 : (w4 == 2) ? kp2 : kp3;
    if ((kw >> bpos) & 1ull) {
      int pos = (int)__popcll(kw & ((1ull << bpos) - 1ull));
      if (w4 > 0) pos += (int)__popcll(kp0);
      if (w4 > 1) pos += (int)__popcll(kp1);
      if (w4 > 2) pos += (int)__popcll(kp2);
      st[pos * 5 + 0] = vals[tid];
      st[pos * 5 + 1] = bx[tid][0];
      st[pos * 5 + 2] = bx[tid][1];
      st[pos * 5 + 3] = bx[tid][2];
      st[pos * 5 + 4] = bx[tid][3];
    }
  }
  __syncthreads();
  float* op = out + (size_t)(b * NCLS + 1 + cm1) * (TOPK * 5);
  if (tid < TOPK * 5 / 4) ((float4*)op)[tid] = ((const float4*)st)[tid];
}

// ---------------- fused fallback (verified R13 kernel), used if ws tiny
__global__ __launch_bounds__(256) void fused_k(
    const float* __restrict__ loc, const float* __restrict__ conf,
    const float* __restrict__ priors, float* __restrict__ out, int B, int P) {
  __shared__ __align__(16) u32 sc[MAXP];
  __shared__ u64 ckey[CAND];
  __shared__ u32 hist[256];
  __shared__ int srt[TOPK];
  __shared__ float bx[TOPK][4];
  __shared__ float vals[TOPK];
  __shared__ __align__(16) float st[TOPK * 5];
  __shared__ u32 s_prefix;
  __shared__ int s_K, s_cnt, s_nv;
  __shared__ u64 s_kw[4];

  const int tid = threadIdx.x;
  const int task = blockIdx.x;
  const int b = task / (NCLS - 1), cm1 = task - b * (NCLS - 1);
  const int c = cm1 + 1;

  if (cm1 == 0) {
    float* bg = out + (size_t)b * (NCLS * TOPK * 5);
    for (int i = tid; i < TOPK * 5; i += 256) bg[i] = 0.0f;
  }
  for (int p = tid; p < P; p += 256) {
    float e[NCLS], mx, S;
    softmax_row(conf + ((size_t)b * P + p) * NCLS, e, mx, S);
    sc[p] = __float_as_uint(__fdiv_rn(e[c], S));
  }
  if (tid == 0) s_cnt = 0;
  __syncthreads();
  u32 prefix = 0; int K = TOPK;
  for (int pass = 0; pass < 4; ++pass) {
    int shift = 24 - 8 * pass;
    u32 known = (pass == 0) ? 0u : (0xFFFFFFFFu << (32 - 8 * pass));
    hist[tid] = 0;
    __syncthreads();
    for (int p = tid; p < P; p += 256) {
      u32 v = sc[p];
      if ((v & known) == prefix) atomicAdd(&hist[(v >> shift) & 0xFFu], 1u);
    }
    __syncthreads();
    for (int off = 1; off < 256; off <<= 1) {
      u32 add = (tid + off < 256) ? hist[tid + off] : 0u;
      __syncthreads();
      hist[tid] += add;
      __syncthreads();
    }
    u32 ge = hist[tid];
    u32 gt = (tid == 255) ? 0u : hist[tid + 1];
    if (ge >= (u32)K && gt < (u32)K) { s_prefix = prefix | ((u32)tid << shift); s_K = K - (int)gt; }
    __syncthreads();
    prefix = s_prefix; K = s_K;
    __syncthreads();
  }
  const u32 T = prefix;
  for (int p = tid; p < P; p += 256) {
    u32 v = sc[p];
    if (v >= T) {
      int slot = atomicAdd(&s_cnt, 1);
      if (slot < CAND) ckey[slot] = ((u64)v << 32) | (u64)(0xFFFFFFFFu - (u32)p);
    }
  }
  __syncthreads();
  int cnt = s_cnt; if (cnt > CAND) cnt = CAND;
  for (int i = tid; i < cnt; i += 256) {
    u64 k = ckey[i]; int r = 0;
    for (int j = 0; j < cnt; ++j) r += (ckey[j] > k) ? 1 : 0;
    if (r < TOPK) srt[r] = i;
  }
  if (tid == 0) s_nv = TOPK;
  __syncthreads();
  if (tid < TOPK) {
    u64 key = ckey[srt[tid]];
    float v = __uint_as_float((u32)(key >> 32));
    int p = (int)(0xFFFFFFFFu - (u32)(key & 0xFFFFFFFFull));
    float4 lp = ((const float4*)loc)[(size_t)b * P + p];
    float4 pr = ((const float4*)priors)[p];
    float tx = __fmul_rn(__fmul_rn(lp.x, 0.1f), pr.z);
    float ty = __fmul_rn(__fmul_rn(lp.y, 0.1f), pr.w);
    float cx = __fadd_rn(pr.x, tx);
    float cy = __fadd_rn(pr.y, ty);
    float w = __fmul_rn(pr.z, expf(__fmul_rn(lp.z, 0.2f)));
    float h = __fmul_rn(pr.w, expf(__fmul_rn(lp.w, 0.2f)));
    float hw = __fmul_rn(w, 0.5f), hh = __fmul_rn(h, 0.5f);
    bx[tid][0] = __fsub_rn(cx, hw);
    bx[tid][1] = __fsub_rn(cy, hh);
    bx[tid][2] = __fadd_rn(cx, hw);
    bx[tid][3] = __fadd_rn(cy, hh);
    vals[tid] = v;
    if (!(v > 0.01f)) atomicMin(&s_nv, tid);
  }
  __syncthreads();
  if (tid < 64) {
    int lane = tid;
    float jx1[4], jy1[4], jx2[4], jy2[4], aj[4];
#pragma unroll
    for (int s = 0; s < 4; ++s) {
      int j = s * 64 + lane;
      if (j < TOPK) { jx1[s]=bx[j][0]; jy1[s]=bx[j][1]; jx2[s]=bx[j][2]; jy2[s]=bx[j][3]; }
      else { jx1[s]=0.f; jy1[s]=0.f; jx2[s]=0.f; jy2[s]=0.f; }
      aj[s] = __fmul_rn(__fsub_rn(jx2[s], jx1[s]), __fsub_rn(jy2[s], jy1[s]));
    }
    u32 keepn = 0;
    int n = s_nv;
    for (int i = 0; i < n; ++i) {
      float ix1 = bx[i][0], iy1 = bx[i][1], ix2 = bx[i][2], iy2 = bx[i][3];
      float ai = __fmul_rn(__fsub_rn(ix2, ix1), __fsub_rn(iy2, iy1));
      bool sup = false;
#pragma unroll
      for (int s = 0; s < 4; ++s) {
        float ww = fmaxf(__fsub_rn(fminf(ix2, jx2[s]), fmaxf(ix1, jx1[s])), 0.0f);
        float hh = fmaxf(__fsub_rn(fminf(iy2, jy2[s]), fmaxf(iy1, jy1[s])), 0.0f);
        float inter = __fmul_rn(ww, hh);
        float den = __fsub_rn(__fadd_rn(ai, aj[s]), inter);
        float iou = __fdiv_rn(inter, den);
        if (((keepn >> s) & 1u) && (iou > 0.45f)) sup = true;
      }
      if (!__any((int)sup)) { if (lane == (i & 63)) keepn |= 1u << (i >> 6); }
    }
    u64 w0 = __ballot((int)(keepn & 1u));
    u64 w1 = __ballot((int)((keepn >> 1) & 1u));
    u64 w2 = __ballot((int)((keepn >> 2) & 1u));
    u64 w3 = __ballot((int)((keepn >> 3) & 1u));
    if (lane == 0) { s_kw[0]=w0; s_kw[1]=w1; s_kw[2]=w2; s_kw[3]=w3; }
  }
  __syncthreads();
  for (int i = tid; i < TOPK * 5; i += 256) st[i] = 0.0f;
  __syncthreads();
  if (tid < TOPK) {
    int w = tid >> 6, bit = tid & 63;
    u64 kwv = s_kw[w];
    if ((kwv >> bit) & 1ull) {
      int pos = (int)__popcll(kwv & ((1ull << bit) - 1ull));
      for (int w2 = 0; w2 < w; ++w2) pos += (int)__popcll(s_kw[w2]);
      st[pos*5+0] = vals[tid];
      st[pos*5+1] = bx[tid][0];
      st[pos*5+2] = bx[tid][1];
      st[pos*5+3] = bx[tid][2];
      st[pos*5+4] = bx[tid][3];
    }
  }
  __syncthreads();
  float* op = out + (size_t)(b * NCLS + 1 + cm1) * (TOPK * 5);
  if (tid < TOPK * 5 / 4) ((float4*)op)[tid] = ((const float4*)st)[tid];
}

extern "C" void kernel_launch(void* const* d_in, const int* in_sizes, int n_in,
                              void* d_out, int out_size, void* d_ws, size_t ws_size,
                              hipStream_t stream) {
  const float* loc    = (const float*)d_in[0];
  const float* conf   = (const float*)d_in[1];
  const float* priors = (const float*)d_in[2];
  float* out = (float*)d_out;

  int P = in_sizes[2] / 4;              // 8732
  int B = in_sizes[0] / (P * 4);        // 128
  int tasks = B * (NCLS - 1);           // 2560
  int BP = B * P;

  size_t probB = (size_t)B * (NCLS - 1) * P * sizeof(float);    // ~89.4 MB

  if (ws_size >= probB) {
    float* probs_t = (float*)d_ws;
    prep2_k<<<(BP + 255) / 256, 256, 0, stream>>>(conf, probs_t, B, P);
    fused2_k<<<tasks, 256, 0, stream>>>(loc, priors, probs_t, out, B, P);
  } else {
    fused_k<<<tasks, 256, 0, stream>>>(loc, conf, priors, out, B, P);
  }
}

// Round 17
// 254.402 us; speedup vs baseline: 1.2883x; 1.0903x over previous
//
#include <hip/hip_runtime.h>
#include <cstdint>

typedef unsigned int u32;
typedef unsigned long long u64;

#define NCLS 21
#define TOPK 200
#define MAXP 8732
#define CAND 384
#define NXCD 8

// Scores: XLA:GPU(gfx950) softmax emulation — exp(x) = v_exp_f32(x*log2e),
// butterfly-tree sum. Everything else stepwise IEEE f32, no fusion.
// ALL numeric values bit-identical to the round-13..16 passing kernels.
#pragma clang fp contract(off)

__device__ __forceinline__ float tri_expf(float x) {
  float t = __fmul_rn(x, 1.4426950408889634f);
  return __builtin_amdgcn_exp2f(t);               // v_exp_f32
}

__device__ __forceinline__ float butterfly_sum21(const float* e) {
  float v[32];
#pragma unroll
  for (int k = 0; k < NCLS; ++k) v[k] = e[k];
#pragma unroll
  for (int k = NCLS; k < 32; ++k) v[k] = 0.0f;
  float a[16], b[8], c4[4], d2[2];
#pragma unroll
  for (int i = 0; i < 16; ++i) a[i] = __fadd_rn(v[i], v[i + 16]);
#pragma unroll
  for (int i = 0; i < 8; ++i) b[i] = __fadd_rn(a[i], a[i + 8]);
#pragma unroll
  for (int i = 0; i < 4; ++i) c4[i] = __fadd_rn(b[i], b[i + 4]);
#pragma unroll
  for (int i = 0; i < 2; ++i) d2[i] = __fadd_rn(c4[i], c4[i + 2]);
  return __fadd_rn(d2[0], d2[1]);
}

__device__ __forceinline__ void softmax_row(const float* __restrict__ row,
                                            float* e, float& mx, float& S) {
  float xs[NCLS];
#pragma unroll
  for (int k = 0; k < NCLS; ++k) xs[k] = row[k];
  mx = xs[0];
#pragma unroll
  for (int k = 1; k < NCLS; ++k) mx = fmaxf(mx, xs[k]);
#pragma unroll
  for (int k = 0; k < NCLS; ++k) e[k] = tri_expf(__fsub_rn(xs[k], mx));
  S = butterfly_sum21(e);
}

__device__ __forceinline__ int swz_task(int bid, int nwg) {
  if ((nwg % NXCD) == 0) return (bid % NXCD) * (nwg / NXCD) + bid / NXCD;
  return bid;
}

// ---------------- prep2: transposed f32 probs (f64 rcp-mul == __fdiv_rn bits)
__global__ __launch_bounds__(256) void prep2_k(const float* __restrict__ conf,
                                               float* __restrict__ probs_t,
                                               int B, int P) {
  int gid = blockIdx.x * 256 + threadIdx.x;
  if (gid >= B * P) return;
  int b = gid / P, p = gid - b * P;
  float e[NCLS], mx, S;
  softmax_row(conf + (size_t)gid * NCLS, e, mx, S);
  double invS = 1.0 / (double)S;
#pragma unroll
  for (int c = 1; c < NCLS; ++c)
    probs_t[((size_t)b * (NCLS - 1) + (c - 1)) * P + p] =
        (float)((double)e[c] * invS);
}

// ---------------- fused select + NMS (TIER2: reads probs_t)
__global__ __launch_bounds__(256) void fused2_k(const float* __restrict__ loc,
                                                const float* __restrict__ priors,
                                                const float* __restrict__ probs_t,
                                                float* __restrict__ out, int B, int P) {
  __shared__ __align__(16) u32 sc[MAXP];
  __shared__ u64 ckey[CAND];
  __shared__ u32 hist[256];
  __shared__ int srt[TOPK];
  __shared__ u32 s_prefix;
  __shared__ int s_K, s_cnt, s_nv;
  __shared__ u64 s_kp[4];

  // overlays on sc (dead after Phase C/D)
  float (*bx)[4] = (float (*)[4])sc;         // bytes [0,3200)
  float* vals  = (float*)(sc + 800);         // bytes [3200,4000)
  float* sarea = (float*)(sc + 1000);        // bytes [4000,4800)
  u64 (*msk)[4] = (u64 (*)[4])(sc + 1200);   // bytes [4800,11200)
  float* st = (float*)(sc + 2800);           // bytes [11200,15200)

  const int tid = threadIdx.x;
  const int task = swz_task(blockIdx.x, gridDim.x);
  const int b = task / (NCLS - 1), cm1 = task - b * (NCLS - 1);

  if (cm1 == 0) {   // zero the background-class rows of this image
    float* bg = out + (size_t)b * (NCLS * TOPK * 5);
    for (int i = tid; i < TOPK * 5; i += 256) bg[i] = 0.0f;
  }
  hist[tid] = 0;
  if (tid == 0) { s_cnt = 0; s_nv = TOPK; }
  __syncthreads();

  // ---- Phase A + radix pass 0 histogram (folded)
  {
    const float* base = probs_t + (size_t)task * P;
    for (int p = tid; p < P; p += 256) {
      u32 v = __float_as_uint(base[p]);
      sc[p] = v;
      atomicAdd(&hist[v >> 24], 1u);
    }
  }
  __syncthreads();

  u32 prefix = 0; int K = TOPK;
  for (int pass = 0; pass < 4; ++pass) {
    int shift = 24 - 8 * pass;
    if (pass > 0) {
      u32 known = 0xFFFFFFFFu << (32 - 8 * pass);
      hist[tid] = 0;
      __syncthreads();
      for (int p = tid; p < P; p += 256) {
        u32 v = sc[p];
        if ((v & known) == prefix) atomicAdd(&hist[(v >> shift) & 0xFFu], 1u);
      }
      __syncthreads();
    }
    // single-wave suffix scan: hist[t] = count(digit >= t)
    if (tid < 64) {
      int l = tid;
      u32 c0 = hist[4 * l], c1 = hist[4 * l + 1], c2 = hist[4 * l + 2], c3 = hist[4 * l + 3];
      u32 s3 = c3, s2 = c2 + s3, s1 = c1 + s2, s0 = c0 + s1;
      u32 tot = s0, acc = tot;
#pragma unroll
      for (int off = 1; off < 64; off <<= 1) {
        u32 o = __shfl_down(acc, off);
        if (l + off < 64) acc += o;
      }
      u32 upper = acc - tot;
      hist[4 * l]     = s0 + upper;
      hist[4 * l + 1] = s1 + upper;
      hist[4 * l + 2] = s2 + upper;
      hist[4 * l + 3] = s3 + upper;
    }
    __syncthreads();
    u32 ge = hist[tid];
    u32 gt = (tid == 255) ? 0u : hist[tid + 1];
    if (ge >= (u32)K && gt < (u32)K) { s_prefix = prefix | ((u32)tid << shift); s_K = K - (int)gt; }
    __syncthreads();
    prefix = s_prefix; K = s_K;
    __syncthreads();
  }
  const u32 T = prefix;

  // ---- Phase C: compact candidates (bits >= T)
  for (int p = tid; p < P; p += 256) {
    u32 v = sc[p];
    if (v >= T) {
      int slot = atomicAdd(&s_cnt, 1);
      if (slot < CAND)
        ckey[slot] = ((u64)v << 32) | (u64)(0xFFFFFFFFu - (u32)p);
    }
  }
  __syncthreads();
  int cnt = s_cnt; if (cnt > CAND) cnt = CAND;

  // ---- Phase D: exact rank by counting
  for (int i = tid; i < cnt; i += 256) {
    u64 k = ckey[i]; int r = 0;
    for (int j = 0; j < cnt; ++j) r += (ckey[j] > k) ? 1 : 0;
    if (r < TOPK) srt[r] = i;
  }
  __syncthreads();   // sc dead from here; overlays become live

  // ---- decode top-200 (bit-identical op sequence) + area hoist
  if (tid < TOPK) {
    u64 key = ckey[srt[tid]];
    float v = __uint_as_float((u32)(key >> 32));
    int p = (int)(0xFFFFFFFFu - (u32)(key & 0xFFFFFFFFull));
    float4 lp = ((const float4*)loc)[(size_t)b * P + p];
    float4 pr = ((const float4*)priors)[p];
    float tx = __fmul_rn(__fmul_rn(lp.x, 0.1f), pr.z);
    float ty = __fmul_rn(__fmul_rn(lp.y, 0.1f), pr.w);
    float cx = __fadd_rn(pr.x, tx);
    float cy = __fadd_rn(pr.y, ty);
    float w = __fmul_rn(pr.z, expf(__fmul_rn(lp.z, 0.2f)));
    float h = __fmul_rn(pr.w, expf(__fmul_rn(lp.w, 0.2f)));
    float hw = __fmul_rn(w, 0.5f), hh = __fmul_rn(h, 0.5f);
    float x1 = __fsub_rn(cx, hw), y1 = __fsub_rn(cy, hh);
    float x2 = __fadd_rn(cx, hw), y2 = __fadd_rn(cy, hh);
    bx[tid][0] = x1; bx[tid][1] = y1; bx[tid][2] = x2; bx[tid][3] = y2;
    vals[tid] = v;
    sarea[tid] = __fmul_rn(__fsub_rn(x2, x1), __fsub_rn(y2, y1));  // ref area bits
    if (!(v > 0.01f)) atomicMin(&s_nv, tid);
  }
  __syncthreads();
  const int n = s_nv;

  // ---- UPPER-TRIANGLE IoU mask matrix (only j > i is ever consulted by the
  // greedy scan: suppression flows strictly from earlier rank to later rank)
  if (tid < n) {
    float rx1 = bx[tid][0], ry1 = bx[tid][1], rx2 = bx[tid][2], ry2 = bx[tid][3];
    float ar = sarea[tid];
    u64 m0 = 0, m1 = 0, m2 = 0, m3 = 0;
    for (int j = tid + 1; j < n; ++j) {
      float jx1 = bx[j][0], jy1 = bx[j][1], jx2 = bx[j][2], jy2 = bx[j][3];
      float aj = sarea[j];
      float ww = fmaxf(__fsub_rn(fminf(rx2, jx2), fmaxf(rx1, jx1)), 0.0f);
      float hh = fmaxf(__fsub_rn(fminf(ry2, jy2), fmaxf(ry1, jy1)), 0.0f);
      float inter = __fmul_rn(ww, hh);
      float den = __fsub_rn(__fadd_rn(ar, aj), inter);
      float iou = __fdiv_rn(inter, den);   // NaN (0/0) -> comparison false
      if (iou > 0.45f) {
        u64 bit = 1ull << (j & 63);
        int w4 = j >> 6;
        if (w4 == 0) m0 |= bit; else if (w4 == 1) m1 |= bit;
        else if (w4 == 2) m2 |= bit; else m3 |= bit;
      }
    }
    msk[tid][0] = m0; msk[tid][1] = m1; msk[tid][2] = m2; msk[tid][3] = m3;
  }
  __syncthreads();

  // ---- scalar greedy scan on wave 0 only; broadcast keep-words via LDS
  if (tid < 64) {
    u64 remv0 = 0, remv1 = 0, remv2 = 0, remv3 = 0;
    u64 kp0 = 0, kp1 = 0, kp2 = 0, kp3 = 0;
    int i = 0;
#define SCAN_WORD(KW, RW)                                              \
    for (int bpos = 0; bpos < 64 && i < n; ++bpos, ++i) {              \
      if (!((RW >> bpos) & 1ull)) {                                    \
        KW |= 1ull << bpos;                                            \
        remv0 |= msk[i][0]; remv1 |= msk[i][1];                        \
        remv2 |= msk[i][2]; remv3 |= msk[i][3];                        \
      }                                                                \
    }
    SCAN_WORD(kp0, remv0)
    SCAN_WORD(kp1, remv1)
    SCAN_WORD(kp2, remv2)
    SCAN_WORD(kp3, remv3)
#undef SCAN_WORD
    if (tid == 0) { s_kp[0] = kp0; s_kp[1] = kp1; s_kp[2] = kp2; s_kp[3] = kp3; }
  }
  __syncthreads();
  const u64 kp0 = s_kp[0], kp1 = s_kp[1], kp2 = s_kp[2], kp3 = s_kp[3];

  for (int i = tid; i < TOPK * 5; i += 256) st[i] = 0.0f;
  __syncthreads();
  if (tid < TOPK) {
    int w4 = tid >> 6, bpos = tid & 63;
    u64 kw = (w4 == 0) ? kp0 : (w4 == 1) ? kp1 : (w4 == 2) ? kp2 : kp3;
    if ((kw >> bpos) & 1ull) {
      int pos = (int)__popcll(kw & ((1ull << bpos) - 1ull));
      if (w4 > 0) pos += (int)__popcll(kp0);
      if (w4 > 1) pos += (int)__popcll(kp1);
      if (w4 > 2) pos += (int)__popcll(kp2);
      st[pos * 5 + 0] = vals[tid];
      st[pos * 5 + 1] = bx[tid][0];
      st[pos * 5 + 2] = bx[tid][1];
      st[pos * 5 + 3] = bx[tid][2];
      st[pos * 5 + 4] = bx[tid][3];
    }
  }
  __syncthreads();
  float* op = out + (size_t)(b * NCLS + 1 + cm1) * (TOPK * 5);
  if (tid < TOPK * 5 / 4) ((float4*)op)[tid] = ((const float4*)st)[tid];
}

// ---------------- fused fallback (verified R13 kernel), used if ws tiny
__global__ __launch_bounds__(256) void fused_k(
    const float* __restrict__ loc, const float* __restrict__ conf,
    const float* __restrict__ priors, float* __restrict__ out, int B, int P) {
  __shared__ __align__(16) u32 sc[MAXP];
  __shared__ u64 ckey[CAND];
  __shared__ u32 hist[256];
  __shared__ int srt[TOPK];
  __shared__ float bx[TOPK][4];
  __shared__ float vals[TOPK];
  __shared__ __align__(16) float st[TOPK * 5];
  __shared__ u32 s_prefix;
  __shared__ int s_K, s_cnt, s_nv;
  __shared__ u64 s_kw[4];

  const int tid = threadIdx.x;
  const int task = blockIdx.x;
  const int b = task / (NCLS - 1), cm1 = task - b * (NCLS - 1);
  const int c = cm1 + 1;

  if (cm1 == 0) {
    float* bg = out + (size_t)b * (NCLS * TOPK * 5);
    for (int i = tid; i < TOPK * 5; i += 256) bg[i] = 0.0f;
  }
  for (int p = tid; p < P; p += 256) {
    float e[NCLS], mx, S;
    softmax_row(conf + ((size_t)b * P + p) * NCLS, e, mx, S);
    sc[p] = __float_as_uint(__fdiv_rn(e[c], S));
  }
  if (tid == 0) s_cnt = 0;
  __syncthreads();
  u32 prefix = 0; int K = TOPK;
  for (int pass = 0; pass < 4; ++pass) {
    int shift = 24 - 8 * pass;
    u32 known = (pass == 0) ? 0u : (0xFFFFFFFFu << (32 - 8 * pass));
    hist[tid] = 0;
    __syncthreads();
    for (int p = tid; p < P; p += 256) {
      u32 v = sc[p];
      if ((v & known) == prefix) atomicAdd(&hist[(v >> shift) & 0xFFu], 1u);
    }
    __syncthreads();
    for (int off = 1; off < 256; off <<= 1) {
      u32 add = (tid + off < 256) ? hist[tid + off] : 0u;
      __syncthreads();
      hist[tid] += add;
      __syncthreads();
    }
    u32 ge = hist[tid];
    u32 gt = (tid == 255) ? 0u : hist[tid + 1];
    if (ge >= (u32)K && gt < (u32)K) { s_prefix = prefix | ((u32)tid << shift); s_K = K - (int)gt; }
    __syncthreads();
    prefix = s_prefix; K = s_K;
    __syncthreads();
  }
  const u32 T = prefix;
  for (int p = tid; p < P; p += 256) {
    u32 v = sc[p];
    if (v >= T) {
      int slot = atomicAdd(&s_cnt, 1);
      if (slot < CAND) ckey[slot] = ((u64)v << 32) | (u64)(0xFFFFFFFFu - (u32)p);
    }
  }
  __syncthreads();
  int cnt = s_cnt; if (cnt > CAND) cnt = CAND;
  for (int i = tid; i < cnt; i += 256) {
    u64 k = ckey[i]; int r = 0;
    for (int j = 0; j < cnt; ++j) r += (ckey[j] > k) ? 1 : 0;
    if (r < TOPK) srt[r] = i;
  }
  if (tid == 0) s_nv = TOPK;
  __syncthreads();
  if (tid < TOPK) {
    u64 key = ckey[srt[tid]];
    float v = __uint_as_float((u32)(key >> 32));
    int p = (int)(0xFFFFFFFFu - (u32)(key & 0xFFFFFFFFull));
    float4 lp = ((const float4*)loc)[(size_t)b * P + p];
    float4 pr = ((const float4*)priors)[p];
    float tx = __fmul_rn(__fmul_rn(lp.x, 0.1f), pr.z);
    float ty = __fmul_rn(__fmul_rn(lp.y, 0.1f), pr.w);
    float cx = __fadd_rn(pr.x, tx);
    float cy = __fadd_rn(pr.y, ty);
    float w = __fmul_rn(pr.z, expf(__fmul_rn(lp.z, 0.2f)));
    float h = __fmul_rn(pr.w, expf(__fmul_rn(lp.w, 0.2f)));
    float hw = __fmul_rn(w, 0.5f), hh = __fmul_rn(h, 0.5f);
    bx[tid][0] = __fsub_rn(cx, hw);
    bx[tid][1] = __fsub_rn(cy, hh);
    bx[tid][2] = __fadd_rn(cx, hw);
    bx[tid][3] = __fadd_rn(cy, hh);
    vals[tid] = v;
    if (!(v > 0.01f)) atomicMin(&s_nv, tid);
  }
  __syncthreads();
  if (tid < 64) {
    int lane = tid;
    float jx1[4], jy1[4], jx2[4], jy2[4], aj[4];
#pragma unroll
    for (int s = 0; s < 4; ++s) {
      int j = s * 64 + lane;
      if (j < TOPK) { jx1[s]=bx[j][0]; jy1[s]=bx[j][1]; jx2[s]=bx[j][2]; jy2[s]=bx[j][3]; }
      else { jx1[s]=0.f; jy1[s]=0.f; jx2[s]=0.f; jy2[s]=0.f; }
      aj[s] = __fmul_rn(__fsub_rn(jx2[s], jx1[s]), __fsub_rn(jy2[s], jy1[s]));
    }
    u32 keepn = 0;
    int n = s_nv;
    for (int i = 0; i < n; ++i) {
      float ix1 = bx[i][0], iy1 = bx[i][1], ix2 = bx[i][2], iy2 = bx[i][3];
      float ai = __fmul_rn(__fsub_rn(ix2, ix1), __fsub_rn(iy2, iy1));
      bool sup = false;
#pragma unroll
      for (int s = 0; s < 4; ++s) {
        float ww = fmaxf(__fsub_rn(fminf(ix2, jx2[s]), fmaxf(ix1, jx1[s])), 0.0f);
        float hh = fmaxf(__fsub_rn(fminf(iy2, jy2[s]), fmaxf(iy1, jy1[s])), 0.0f);
        float inter = __fmul_rn(ww, hh);
        float den = __fsub_rn(__fadd_rn(ai, aj[s]), inter);
        float iou = __fdiv_rn(inter, den);
        if (((keepn >> s) & 1u) && (iou > 0.45f)) sup = true;
      }
      if (!__any((int)sup)) { if (lane == (i & 63)) keepn |= 1u << (i >> 6); }
    }
    u64 w0 = __ballot((int)(keepn & 1u));
    u64 w1 = __ballot((int)((keepn >> 1) & 1u));
    u64 w2 = __ballot((int)((keepn >> 2) & 1u));
    u64 w3 = __ballot((int)((keepn >> 3) & 1u));
    if (lane == 0) { s_kw[0]=w0; s_kw[1]=w1; s_kw[2]=w2; s_kw[3]=w3; }
  }
  __syncthreads();
  for (int i = tid; i < TOPK * 5; i += 256) st[i] = 0.0f;
  __syncthreads();
  if (tid < TOPK) {
    int w = tid >> 6, bit = tid & 63;
    u64 kwv = s_kw[w];
    if ((kwv >> bit) & 1ull) {
      int pos = (int)__popcll(kwv & ((1ull << bit) - 1ull));
      for (int w2 = 0; w2 < w; ++w2) pos += (int)__popcll(s_kw[w2]);
      st[pos*5+0] = vals[tid];
      st[pos*5+1] = bx[tid][0];
      st[pos*5+2] = bx[tid][1];
      st[pos*5+3] = bx[tid][2];
      st[pos*5+4] = bx[tid][3];
    }
  }
  __syncthreads();
  float* op = out + (size_t)(b * NCLS + 1 + cm1) * (TOPK * 5);
  if (tid < TOPK * 5 / 4) ((float4*)op)[tid] = ((const float4*)st)[tid];
}

extern "C" void kernel_launch(void* const* d_in, const int* in_sizes, int n_in,
                              void* d_out, int out_size, void* d_ws, size_t ws_size,
                              hipStream_t stream) {
  const float* loc    = (const float*)d_in[0];
  const float* conf   = (const float*)d_in[1];
  const float* priors = (const float*)d_in[2];
  float* out = (float*)d_out;

  int P = in_sizes[2] / 4;              // 8732
  int B = in_sizes[0] / (P * 4);        // 128
  int tasks = B * (NCLS - 1);           // 2560
  int BP = B * P;

  size_t probB = (size_t)B * (NCLS - 1) * P * sizeof(float);    // ~89.4 MB

  if (ws_size >= probB) {
    float* probs_t = (float*)d_ws;
    prep2_k<<<(BP + 255) / 256, 256, 0, stream>>>(conf, probs_t, B, P);
    fused2_k<<<tasks, 256, 0, stream>>>(loc, priors, probs_t, out, B, P);
  } else {
    fused_k<<<tasks, 256, 0, stream>>>(loc, conf, priors, out, B, P);
  }
}

// Round 18
// 237.220 us; speedup vs baseline: 1.3816x; 1.0724x over previous
//
#include <hip/hip_runtime.h>
#include <cstdint>

typedef unsigned int u32;
typedef unsigned long long u64;

#define NCLS 21
#define TOPK 200
#define MAXP 8732
#define CAND 384
#define NXCD 8

// Scores: XLA:GPU(gfx950) softmax emulation — exp(x) = v_exp_f32(x*log2e),
// butterfly-tree sum. Everything else stepwise IEEE f32, no fusion.
// ALL numeric values bit-identical to the round-13..17 passing kernels.
#pragma clang fp contract(off)

__device__ __forceinline__ float tri_expf(float x) {
  float t = __fmul_rn(x, 1.4426950408889634f);
  return __builtin_amdgcn_exp2f(t);               // v_exp_f32
}

__device__ __forceinline__ float butterfly_sum21(const float* e) {
  float v[32];
#pragma unroll
  for (int k = 0; k < NCLS; ++k) v[k] = e[k];
#pragma unroll
  for (int k = NCLS; k < 32; ++k) v[k] = 0.0f;
  float a[16], b[8], c4[4], d2[2];
#pragma unroll
  for (int i = 0; i < 16; ++i) a[i] = __fadd_rn(v[i], v[i + 16]);
#pragma unroll
  for (int i = 0; i < 8; ++i) b[i] = __fadd_rn(a[i], a[i + 8]);
#pragma unroll
  for (int i = 0; i < 4; ++i) c4[i] = __fadd_rn(b[i], b[i + 4]);
#pragma unroll
  for (int i = 0; i < 2; ++i) d2[i] = __fadd_rn(c4[i], c4[i + 2]);
  return __fadd_rn(d2[0], d2[1]);
}

__device__ __forceinline__ void softmax_row(const float* __restrict__ row,
                                            float* e, float& mx, float& S) {
  float xs[NCLS];
#pragma unroll
  for (int k = 0; k < NCLS; ++k) xs[k] = row[k];
  mx = xs[0];
#pragma unroll
  for (int k = 1; k < NCLS; ++k) mx = fmaxf(mx, xs[k]);
#pragma unroll
  for (int k = 0; k < NCLS; ++k) e[k] = tri_expf(__fsub_rn(xs[k], mx));
  S = butterfly_sum21(e);
}

__device__ __forceinline__ int swz_task(int bid, int nwg) {
  if ((nwg % NXCD) == 0) return (bid % NXCD) * (nwg / NXCD) + bid / NXCD;
  return bid;
}

// ---------------- prep2: transposed f32 probs (f64 rcp-mul == __fdiv_rn bits)
__global__ __launch_bounds__(256) void prep2_k(const float* __restrict__ conf,
                                               float* __restrict__ probs_t,
                                               int B, int P) {
  int gid = blockIdx.x * 256 + threadIdx.x;
  if (gid >= B * P) return;
  int b = gid / P, p = gid - b * P;
  float e[NCLS], mx, S;
  softmax_row(conf + (size_t)gid * NCLS, e, mx, S);
  double invS = 1.0 / (double)S;
#pragma unroll
  for (int c = 1; c < NCLS; ++c)
    probs_t[((size_t)b * (NCLS - 1) + (c - 1)) * P + p] =
        (float)((double)e[c] * invS);
}

// ---------------- fused select + NMS, small-LDS version (high occupancy):
// radix passes re-read L3-resident probs_t instead of caching bits in LDS.
__global__ __launch_bounds__(256) void fused3_k(const float* __restrict__ loc,
                                                const float* __restrict__ priors,
                                                const float* __restrict__ probs_t,
                                                float* __restrict__ out, int B, int P) {
  __shared__ __align__(16) unsigned char smem[16096];
  u32* hist = (u32*)smem;                          // [0,1024)    (dead after radix)
  u64* ckey = (u64*)(smem + 1024);                 // [1024,4096) (dead after decode)
  int* srt  = (int*)(smem + 4096);                 // [4096,4896) (dead after decode)
  float (*bx)[4] = (float (*)[4])(smem + 4896);    // [4896,8096)
  float* vals  = (float*)(smem + 8096);            // [8096,8896)
  float* sarea = (float*)(smem + 8896);            // [8896,9696)
  u64 (*msk)[4] = (u64 (*)[4])(smem + 9696);       // [9696,16096)
  float* st = (float*)smem;                        // overlay [0,4000) after decode
  __shared__ u32 s_prefix;
  __shared__ int s_K, s_cnt, s_nv;
  __shared__ u64 s_kp[4];

  const int tid = threadIdx.x;
  const int task = swz_task(blockIdx.x, gridDim.x);
  const int b = task / (NCLS - 1), cm1 = task - b * (NCLS - 1);
  const float* base = probs_t + (size_t)task * P;

  if (cm1 == 0) {   // zero the background-class rows of this image
    float* bg = out + (size_t)b * (NCLS * TOPK * 5);
    for (int i = tid; i < TOPK * 5; i += 256) bg[i] = 0.0f;
  }
  hist[tid] = 0;
  if (tid == 0) { s_cnt = 0; s_nv = TOPK; }
  __syncthreads();

  // ---- radix pass 0 histogram, folded into the first streaming read
  for (int p = tid; p < P; p += 256)
    atomicAdd(&hist[__float_as_uint(base[p]) >> 24], 1u);
  __syncthreads();

  u32 prefix = 0; int K = TOPK;
  for (int pass = 0; pass < 4; ++pass) {
    int shift = 24 - 8 * pass;
    if (pass > 0) {
      u32 known = 0xFFFFFFFFu << (32 - 8 * pass);
      hist[tid] = 0;
      __syncthreads();
      for (int p = tid; p < P; p += 256) {
        u32 v = __float_as_uint(base[p]);
        if ((v & known) == prefix) atomicAdd(&hist[(v >> shift) & 0xFFu], 1u);
      }
      __syncthreads();
    }
    // single-wave suffix scan: hist[t] = count(digit >= t)
    if (tid < 64) {
      int l = tid;
      u32 c0 = hist[4 * l], c1 = hist[4 * l + 1], c2 = hist[4 * l + 2], c3 = hist[4 * l + 3];
      u32 s3 = c3, s2 = c2 + s3, s1 = c1 + s2, s0 = c0 + s1;
      u32 tot = s0, acc = tot;
#pragma unroll
      for (int off = 1; off < 64; off <<= 1) {
        u32 o = __shfl_down(acc, off);
        if (l + off < 64) acc += o;
      }
      u32 upper = acc - tot;
      hist[4 * l]     = s0 + upper;
      hist[4 * l + 1] = s1 + upper;
      hist[4 * l + 2] = s2 + upper;
      hist[4 * l + 3] = s3 + upper;
    }
    __syncthreads();
    u32 ge = hist[tid];
    u32 gt = (tid == 255) ? 0u : hist[tid + 1];
    if (ge >= (u32)K && gt < (u32)K) { s_prefix = prefix | ((u32)tid << shift); s_K = K - (int)gt; }
    __syncthreads();
    prefix = s_prefix; K = s_K;
    __syncthreads();
  }
  const u32 T = prefix;

  // ---- compact candidates (bits >= T) — streaming re-read
  for (int p = tid; p < P; p += 256) {
    u32 v = __float_as_uint(base[p]);
    if (v >= T) {
      int slot = atomicAdd(&s_cnt, 1);
      if (slot < CAND)
        ckey[slot] = ((u64)v << 32) | (u64)(0xFFFFFFFFu - (u32)p);
    }
  }
  __syncthreads();
  int cnt = s_cnt; if (cnt > CAND) cnt = CAND;

  // ---- exact rank by counting
  for (int i = tid; i < cnt; i += 256) {
    u64 k = ckey[i]; int r = 0;
    for (int j = 0; j < cnt; ++j) r += (ckey[j] > k) ? 1 : 0;
    if (r < TOPK) srt[r] = i;
  }
  __syncthreads();

  // ---- decode top-200 (bit-identical op sequence) + area hoist
  if (tid < TOPK) {
    u64 key = ckey[srt[tid]];
    float v = __uint_as_float((u32)(key >> 32));
    int p = (int)(0xFFFFFFFFu - (u32)(key & 0xFFFFFFFFull));
    float4 lp = ((const float4*)loc)[(size_t)b * P + p];
    float4 pr = ((const float4*)priors)[p];
    float tx = __fmul_rn(__fmul_rn(lp.x, 0.1f), pr.z);
    float ty = __fmul_rn(__fmul_rn(lp.y, 0.1f), pr.w);
    float cx = __fadd_rn(pr.x, tx);
    float cy = __fadd_rn(pr.y, ty);
    float w = __fmul_rn(pr.z, expf(__fmul_rn(lp.z, 0.2f)));
    float h = __fmul_rn(pr.w, expf(__fmul_rn(lp.w, 0.2f)));
    float hw = __fmul_rn(w, 0.5f), hh = __fmul_rn(h, 0.5f);
    float x1 = __fsub_rn(cx, hw), y1 = __fsub_rn(cy, hh);
    float x2 = __fadd_rn(cx, hw), y2 = __fadd_rn(cy, hh);
    bx[tid][0] = x1; bx[tid][1] = y1; bx[tid][2] = x2; bx[tid][3] = y2;
    vals[tid] = v;
    sarea[tid] = __fmul_rn(__fsub_rn(x2, x1), __fsub_rn(y2, y1));  // ref area bits
    if (!(v > 0.01f)) atomicMin(&s_nv, tid);
  }
  __syncthreads();
  const int n = s_nv;

  // ---- upper-triangle IoU mask matrix (only j > i consulted by the scan)
  if (tid < n) {
    float rx1 = bx[tid][0], ry1 = bx[tid][1], rx2 = bx[tid][2], ry2 = bx[tid][3];
    float ar = sarea[tid];
    u64 m0 = 0, m1 = 0, m2 = 0, m3 = 0;
    for (int j = tid + 1; j < n; ++j) {
      float jx1 = bx[j][0], jy1 = bx[j][1], jx2 = bx[j][2], jy2 = bx[j][3];
      float aj = sarea[j];
      float ww = fmaxf(__fsub_rn(fminf(rx2, jx2), fmaxf(rx1, jx1)), 0.0f);
      float hh = fmaxf(__fsub_rn(fminf(ry2, jy2), fmaxf(ry1, jy1)), 0.0f);
      float inter = __fmul_rn(ww, hh);
      float den = __fsub_rn(__fadd_rn(ar, aj), inter);
      float iou = __fdiv_rn(inter, den);   // NaN (0/0) -> comparison false
      if (iou > 0.45f) {
        u64 bit = 1ull << (j & 63);
        int w4 = j >> 6;
        if (w4 == 0) m0 |= bit; else if (w4 == 1) m1 |= bit;
        else if (w4 == 2) m2 |= bit; else m3 |= bit;
      }
    }
    msk[tid][0] = m0; msk[tid][1] = m1; msk[tid][2] = m2; msk[tid][3] = m3;
  }
  __syncthreads();

  // ---- scalar greedy scan on wave 0 only; broadcast keep-words via LDS
  if (tid < 64) {
    u64 remv0 = 0, remv1 = 0, remv2 = 0, remv3 = 0;
    u64 kp0 = 0, kp1 = 0, kp2 = 0, kp3 = 0;
    int i = 0;
#define SCAN_WORD(KW, RW)                                              \
    for (int bpos = 0; bpos < 64 && i < n; ++bpos, ++i) {              \
      if (!((RW >> bpos) & 1ull)) {                                    \
        KW |= 1ull << bpos;                                            \
        remv0 |= msk[i][0]; remv1 |= msk[i][1];                        \
        remv2 |= msk[i][2]; remv3 |= msk[i][3];                        \
      }                                                                \
    }
    SCAN_WORD(kp0, remv0)
    SCAN_WORD(kp1, remv1)
    SCAN_WORD(kp2, remv2)
    SCAN_WORD(kp3, remv3)
#undef SCAN_WORD
    if (tid == 0) { s_kp[0] = kp0; s_kp[1] = kp1; s_kp[2] = kp2; s_kp[3] = kp3; }
  }
  __syncthreads();
  const u64 kp0 = s_kp[0], kp1 = s_kp[1], kp2 = s_kp[2], kp3 = s_kp[3];

  for (int i = tid; i < TOPK * 5; i += 256) st[i] = 0.0f;   // st overlays hist/ckey (dead)
  __syncthreads();
  if (tid < TOPK) {
    int w4 = tid >> 6, bpos = tid & 63;
    u64 kw = (w4 == 0) ? kp0 : (w4 == 1) ? kp1 : (w4 == 2) ? kp2 : kp3;
    if ((kw >> bpos) & 1ull) {
      int pos = (int)__popcll(kw & ((1ull << bpos) - 1ull));
      if (w4 > 0) pos += (int)__popcll(kp0);
      if (w4 > 1) pos += (int)__popcll(kp1);
      if (w4 > 2) pos += (int)__popcll(kp2);
      st[pos * 5 + 0] = vals[tid];
      st[pos * 5 + 1] = bx[tid][0];
      st[pos * 5 + 2] = bx[tid][1];
      st[pos * 5 + 3] = bx[tid][2];
      st[pos * 5 + 4] = bx[tid][3];
    }
  }
  __syncthreads();
  float* op = out + (size_t)(b * NCLS + 1 + cm1) * (TOPK * 5);
  if (tid < TOPK * 5 / 4) ((float4*)op)[tid] = ((const float4*)st)[tid];
}

// ---------------- fused fallback (verified R13 kernel), used if ws tiny
__global__ __launch_bounds__(256) void fused_k(
    const float* __restrict__ loc, const float* __restrict__ conf,
    const float* __restrict__ priors, float* __restrict__ out, int B, int P) {
  __shared__ __align__(16) u32 sc[MAXP];
  __shared__ u64 ckey[CAND];
  __shared__ u32 hist[256];
  __shared__ int srt[TOPK];
  __shared__ float bx[TOPK][4];
  __shared__ float vals[TOPK];
  __shared__ __align__(16) float st[TOPK * 5];
  __shared__ u32 s_prefix;
  __shared__ int s_K, s_cnt, s_nv;
  __shared__ u64 s_kw[4];

  const int tid = threadIdx.x;
  const int task = blockIdx.x;
  const int b = task / (NCLS - 1), cm1 = task - b * (NCLS - 1);
  const int c = cm1 + 1;

  if (cm1 == 0) {
    float* bg = out + (size_t)b * (NCLS * TOPK * 5);
    for (int i = tid; i < TOPK * 5; i += 256) bg[i] = 0.0f;
  }
  for (int p = tid; p < P; p += 256) {
    float e[NCLS], mx, S;
    softmax_row(conf + ((size_t)b * P + p) * NCLS, e, mx, S);
    sc[p] = __float_as_uint(__fdiv_rn(e[c], S));
  }
  if (tid == 0) s_cnt = 0;
  __syncthreads();
  u32 prefix = 0; int K = TOPK;
  for (int pass = 0; pass < 4; ++pass) {
    int shift = 24 - 8 * pass;
    u32 known = (pass == 0) ? 0u : (0xFFFFFFFFu << (32 - 8 * pass));
    hist[tid] = 0;
    __syncthreads();
    for (int p = tid; p < P; p += 256) {
      u32 v = sc[p];
      if ((v & known) == prefix) atomicAdd(&hist[(v >> shift) & 0xFFu], 1u);
    }
    __syncthreads();
    for (int off = 1; off < 256; off <<= 1) {
      u32 add = (tid + off < 256) ? hist[tid + off] : 0u;
      __syncthreads();
      hist[tid] += add;
      __syncthreads();
    }
    u32 ge = hist[tid];
    u32 gt = (tid == 255) ? 0u : hist[tid + 1];
    if (ge >= (u32)K && gt < (u32)K) { s_prefix = prefix | ((u32)tid << shift); s_K = K - (int)gt; }
    __syncthreads();
    prefix = s_prefix; K = s_K;
    __syncthreads();
  }
  const u32 T = prefix;
  for (int p = tid; p < P; p += 256) {
    u32 v = sc[p];
    if (v >= T) {
      int slot = atomicAdd(&s_cnt, 1);
      if (slot < CAND) ckey[slot] = ((u64)v << 32) | (u64)(0xFFFFFFFFu - (u32)p);
    }
  }
  __syncthreads();
  int cnt = s_cnt; if (cnt > CAND) cnt = CAND;
  for (int i = tid; i < cnt; i += 256) {
    u64 k = ckey[i]; int r = 0;
    for (int j = 0; j < cnt; ++j) r += (ckey[j] > k) ? 1 : 0;
    if (r < TOPK) srt[r] = i;
  }
  if (tid == 0) s_nv = TOPK;
  __syncthreads();
  if (tid < TOPK) {
    u64 key = ckey[srt[tid]];
    float v = __uint_as_float((u32)(key >> 32));
    int p = (int)(0xFFFFFFFFu - (u32)(key & 0xFFFFFFFFull));
    float4 lp = ((const float4*)loc)[(size_t)b * P + p];
    float4 pr = ((const float4*)priors)[p];
    float tx = __fmul_rn(__fmul_rn(lp.x, 0.1f), pr.z);
    float ty = __fmul_rn(__fmul_rn(lp.y, 0.1f), pr.w);
    float cx = __fadd_rn(pr.x, tx);
    float cy = __fadd_rn(pr.y, ty);
    float w = __fmul_rn(pr.z, expf(__fmul_rn(lp.z, 0.2f)));
    float h = __fmul_rn(pr.w, expf(__fmul_rn(lp.w, 0.2f)));
    float hw = __fmul_rn(w, 0.5f), hh = __fmul_rn(h, 0.5f);
    bx[tid][0] = __fsub_rn(cx, hw);
    bx[tid][1] = __fsub_rn(cy, hh);
    bx[tid][2] = __fadd_rn(cx, hw);
    bx[tid][3] = __fadd_rn(cy, hh);
    vals[tid] = v;
    if (!(v > 0.01f)) atomicMin(&s_nv, tid);
  }
  __syncthreads();
  if (tid < 64) {
    int lane = tid;
    float jx1[4], jy1[4], jx2[4], jy2[4], aj[4];
#pragma unroll
    for (int s = 0; s < 4; ++s) {
      int j = s * 64 + lane;
      if (j < TOPK) { jx1[s]=bx[j][0]; jy1[s]=bx[j][1]; jx2[s]=bx[j][2]; jy2[s]=bx[j][3]; }
      else { jx1[s]=0.f; jy1[s]=0.f; jx2[s]=0.f; jy2[s]=0.f; }
      aj[s] = __fmul_rn(__fsub_rn(jx2[s], jx1[s]), __fsub_rn(jy2[s], jy1[s]));
    }
    u32 keepn = 0;
    int n = s_nv;
    for (int i = 0; i < n; ++i) {
      float ix1 = bx[i][0], iy1 = bx[i][1], ix2 = bx[i][2], iy2 = bx[i][3];
      float ai = __fmul_rn(__fsub_rn(ix2, ix1), __fsub_rn(iy2, iy1));
      bool sup = false;
#pragma unroll
      for (int s = 0; s < 4; ++s) {
        float ww = fmaxf(__fsub_rn(fminf(ix2, jx2[s]), fmaxf(ix1, jx1[s])), 0.0f);
        float hh = fmaxf(__fsub_rn(fminf(iy2, jy2[s]), fmaxf(iy1, jy1[s])), 0.0f);
        float inter = __fmul_rn(ww, hh);
        float den = __fsub_rn(__fadd_rn(ai, aj[s]), inter);
        float iou = __fdiv_rn(inter, den);
        if (((keepn >> s) & 1u) && (iou > 0.45f)) sup = true;
      }
      if (!__any((int)sup)) { if (lane == (i & 63)) keepn |= 1u << (i >> 6); }
    }
    u64 w0 = __ballot((int)(keepn & 1u));
    u64 w1 = __ballot((int)((keepn >> 1) & 1u));
    u64 w2 = __ballot((int)((keepn >> 2) & 1u));
    u64 w3 = __ballot((int)((keepn >> 3) & 1u));
    if (lane == 0) { s_kw[0]=w0; s_kw[1]=w1; s_kw[2]=w2; s_kw[3]=w3; }
  }
  __syncthreads();
  for (int i = tid; i < TOPK * 5; i += 256) st[i] = 0.0f;
  __syncthreads();
  if (tid < TOPK) {
    int w = tid >> 6, bit = tid & 63;
    u64 kwv = s_kw[w];
    if ((kwv >> bit) & 1ull) {
      int pos = (int)__popcll(kwv & ((1ull << bit) - 1ull));
      for (int w2 = 0; w2 < w; ++w2) pos += (int)__popcll(s_kw[w2]);
      st[pos*5+0] = vals[tid];
      st[pos*5+1] = bx[tid][0];
      st[pos*5+2] = bx[tid][1];
      st[pos*5+3] = bx[tid][2];
      st[pos*5+4] = bx[tid][3];
    }
  }
  __syncthreads();
  float* op = out + (size_t)(b * NCLS + 1 + cm1) * (TOPK * 5);
  if (tid < TOPK * 5 / 4) ((float4*)op)[tid] = ((const float4*)st)[tid];
}

extern "C" void kernel_launch(void* const* d_in, const int* in_sizes, int n_in,
                              void* d_out, int out_size, void* d_ws, size_t ws_size,
                              hipStream_t stream) {
  const float* loc    = (const float*)d_in[0];
  const float* conf   = (const float*)d_in[1];
  const float* priors = (const float*)d_in[2];
  float* out = (float*)d_out;

  int P = in_sizes[2] / 4;              // 8732
  int B = in_sizes[0] / (P * 4);        // 128
  int tasks = B * (NCLS - 1);           // 2560
  int BP = B * P;

  size_t probB = (size_t)B * (NCLS - 1) * P * sizeof(float);    // ~89.4 MB

  if (ws_size >= probB) {
    float* probs_t = (float*)d_ws;
    prep2_k<<<(BP + 255) / 256, 256, 0, stream>>>(conf, probs_t, B, P);
    fused3_k<<<tasks, 256, 0, stream>>>(loc, priors, probs_t, out, B, P);
  } else {
    fused_k<<<tasks, 256, 0, stream>>>(loc, conf, priors, out, B, P);
  }
}

// Round 19
// 178.683 us; speedup vs baseline: 1.8342x; 1.3276x over previous
//
#include <hip/hip_runtime.h>
#include <cstdint>

typedef unsigned int u32;
typedef unsigned long long u64;

#define NCLS 21
#define TOPK 200
#define MAXP 8732
#define CAND 384
#define NXCD 8
#define NREG 9   // ceil((MAXP/4)/256)

// Scores: XLA:GPU(gfx950) softmax emulation — exp(x) = v_exp_f32(x*log2e),
// butterfly-tree sum. Everything else stepwise IEEE f32, no fusion.
// ALL numeric values bit-identical to the round-13..18 passing kernels.
#pragma clang fp contract(off)

__device__ __forceinline__ float tri_expf(float x) {
  float t = __fmul_rn(x, 1.4426950408889634f);
  return __builtin_amdgcn_exp2f(t);               // v_exp_f32
}

__device__ __forceinline__ float butterfly_sum21(const float* e) {
  float v[32];
#pragma unroll
  for (int k = 0; k < NCLS; ++k) v[k] = e[k];
#pragma unroll
  for (int k = NCLS; k < 32; ++k) v[k] = 0.0f;
  float a[16], b[8], c4[4], d2[2];
#pragma unroll
  for (int i = 0; i < 16; ++i) a[i] = __fadd_rn(v[i], v[i + 16]);
#pragma unroll
  for (int i = 0; i < 8; ++i) b[i] = __fadd_rn(a[i], a[i + 8]);
#pragma unroll
  for (int i = 0; i < 4; ++i) c4[i] = __fadd_rn(b[i], b[i + 4]);
#pragma unroll
  for (int i = 0; i < 2; ++i) d2[i] = __fadd_rn(c4[i], c4[i + 2]);
  return __fadd_rn(d2[0], d2[1]);
}

__device__ __forceinline__ void softmax_row(const float* __restrict__ row,
                                            float* e, float& mx, float& S) {
  float xs[NCLS];
#pragma unroll
  for (int k = 0; k < NCLS; ++k) xs[k] = row[k];
  mx = xs[0];
#pragma unroll
  for (int k = 1; k < NCLS; ++k) mx = fmaxf(mx, xs[k]);
#pragma unroll
  for (int k = 0; k < NCLS; ++k) e[k] = tri_expf(__fsub_rn(xs[k], mx));
  S = butterfly_sum21(e);
}

__device__ __forceinline__ int swz_task(int bid, int nwg) {
  if ((nwg % NXCD) == 0) return (bid % NXCD) * (nwg / NXCD) + bid / NXCD;
  return bid;
}

// ---------------- prep2: transposed f32 probs (f64 rcp-mul == __fdiv_rn bits)
__global__ __launch_bounds__(256) void prep2_k(const float* __restrict__ conf,
                                               float* __restrict__ probs_t,
                                               int B, int P) {
  int gid = blockIdx.x * 256 + threadIdx.x;
  if (gid >= B * P) return;
  int b = gid / P, p = gid - b * P;
  float e[NCLS], mx, S;
  softmax_row(conf + (size_t)gid * NCLS, e, mx, S);
  double invS = 1.0 / (double)S;
#pragma unroll
  for (int c = 1; c < NCLS; ++c)
    probs_t[((size_t)b * (NCLS - 1) + (c - 1)) * P + p] =
        (float)((double)e[c] * invS);
}

// ---------------- fused select + NMS, register-resident scores:
// ONE streaming read of probs_t into 36 regs/thread; radix passes + compact
// run from registers. Counts/sets identical -> bit-identical output.
__global__ __launch_bounds__(256) void fused4_k(const float* __restrict__ loc,
                                                const float* __restrict__ priors,
                                                const float* __restrict__ probs_t,
                                                float* __restrict__ out, int B, int P) {
  __shared__ __align__(16) unsigned char smem[16096];
  u32* hist = (u32*)smem;                          // [0,1024)    (dead after radix)
  u64* ckey = (u64*)(smem + 1024);                 // [1024,4096) (dead after decode)
  int* srt  = (int*)(smem + 4096);                 // [4096,4896) (dead after decode)
  float (*bx)[4] = (float (*)[4])(smem + 4896);    // [4896,8096)
  float* vals  = (float*)(smem + 8096);            // [8096,8896)
  float* sarea = (float*)(smem + 8896);            // [8896,9696)
  u64 (*msk)[4] = (u64 (*)[4])(smem + 9696);       // [9696,16096)
  float* st = (float*)smem;                        // overlay [0,4000) after decode
  __shared__ u32 s_prefix;
  __shared__ int s_K, s_cnt, s_nv;
  __shared__ u64 s_kp[4];

  const int tid = threadIdx.x;
  const int task = swz_task(blockIdx.x, gridDim.x);
  const int b = task / (NCLS - 1), cm1 = task - b * (NCLS - 1);
  const int n4 = P >> 2;                            // P % 4 == 0 (host-guarded)
  const float4* base4 = (const float4*)(probs_t + (size_t)task * P);

  if (cm1 == 0) {   // zero the background-class rows of this image
    float* bg = out + (size_t)b * (NCLS * TOPK * 5);
    for (int i = tid; i < TOPK * 5; i += 256) bg[i] = 0.0f;
  }
  hist[tid] = 0;
  if (tid == 0) { s_cnt = 0; s_nv = TOPK; }
  __syncthreads();

  // ---- single streaming read -> registers, pass-0 histogram folded in
  u32 v[NREG * 4];
#pragma unroll
  for (int k = 0; k < NREG; ++k) {
    int i4 = tid + k * 256;
    bool ok = (i4 < n4);
    float4 f = ok ? base4[i4] : make_float4(0.f, 0.f, 0.f, 0.f);
    v[4 * k + 0] = __float_as_uint(f.x);
    v[4 * k + 1] = __float_as_uint(f.y);
    v[4 * k + 2] = __float_as_uint(f.z);
    v[4 * k + 3] = __float_as_uint(f.w);
    if (ok) {
      atomicAdd(&hist[v[4 * k + 0] >> 24], 1u);
      atomicAdd(&hist[v[4 * k + 1] >> 24], 1u);
      atomicAdd(&hist[v[4 * k + 2] >> 24], 1u);
      atomicAdd(&hist[v[4 * k + 3] >> 24], 1u);
    }
  }
  __syncthreads();

  u32 prefix = 0; int K = TOPK;
  for (int pass = 0; pass < 4; ++pass) {
    int shift = 24 - 8 * pass;
    if (pass > 0) {
      u32 known = 0xFFFFFFFFu << (32 - 8 * pass);
      hist[tid] = 0;
      __syncthreads();
#pragma unroll
      for (int k = 0; k < NREG; ++k) {
        bool ok = (tid + k * 256 < n4);
#pragma unroll
        for (int j = 0; j < 4; ++j) {
          u32 val = v[4 * k + j];
          if (ok && (val & known) == prefix)
            atomicAdd(&hist[(val >> shift) & 0xFFu], 1u);
        }
      }
      __syncthreads();
    }
    // single-wave suffix scan: hist[t] = count(digit >= t)
    if (tid < 64) {
      int l = tid;
      u32 c0 = hist[4 * l], c1 = hist[4 * l + 1], c2 = hist[4 * l + 2], c3 = hist[4 * l + 3];
      u32 s3 = c3, s2 = c2 + s3, s1 = c1 + s2, s0 = c0 + s1;
      u32 tot = s0, acc = tot;
#pragma unroll
      for (int off = 1; off < 64; off <<= 1) {
        u32 o = __shfl_down(acc, off);
        if (l + off < 64) acc += o;
      }
      u32 upper = acc - tot;
      hist[4 * l]     = s0 + upper;
      hist[4 * l + 1] = s1 + upper;
      hist[4 * l + 2] = s2 + upper;
      hist[4 * l + 3] = s3 + upper;
    }
    __syncthreads();
    u32 ge = hist[tid];
    u32 gt = (tid == 255) ? 0u : hist[tid + 1];
    if (ge >= (u32)K && gt < (u32)K) { s_prefix = prefix | ((u32)tid << shift); s_K = K - (int)gt; }
    __syncthreads();
    prefix = s_prefix; K = s_K;
    __syncthreads();
  }
  const u32 T = prefix;

  // ---- compact candidates (bits >= T) from registers
#pragma unroll
  for (int k = 0; k < NREG; ++k) {
    int i4 = tid + k * 256;
    bool ok = (i4 < n4);
#pragma unroll
    for (int j = 0; j < 4; ++j) {
      u32 val = v[4 * k + j];
      if (ok && val >= T) {
        int slot = atomicAdd(&s_cnt, 1);
        if (slot < CAND)
          ckey[slot] = ((u64)val << 32) | (u64)(0xFFFFFFFFu - (u32)(4 * i4 + j));
      }
    }
  }
  __syncthreads();
  int cnt = s_cnt; if (cnt > CAND) cnt = CAND;

  // ---- exact rank by counting (set-identical keys -> identical order)
  for (int i = tid; i < cnt; i += 256) {
    u64 k = ckey[i]; int r = 0;
    for (int j = 0; j < cnt; ++j) r += (ckey[j] > k) ? 1 : 0;
    if (r < TOPK) srt[r] = i;
  }
  __syncthreads();

  // ---- decode top-200 (bit-identical op sequence) + area hoist
  if (tid < TOPK) {
    u64 key = ckey[srt[tid]];
    float vv = __uint_as_float((u32)(key >> 32));
    int p = (int)(0xFFFFFFFFu - (u32)(key & 0xFFFFFFFFull));
    float4 lp = ((const float4*)loc)[(size_t)b * P + p];
    float4 pr = ((const float4*)priors)[p];
    float tx = __fmul_rn(__fmul_rn(lp.x, 0.1f), pr.z);
    float ty = __fmul_rn(__fmul_rn(lp.y, 0.1f), pr.w);
    float cx = __fadd_rn(pr.x, tx);
    float cy = __fadd_rn(pr.y, ty);
    float w = __fmul_rn(pr.z, expf(__fmul_rn(lp.z, 0.2f)));
    float h = __fmul_rn(pr.w, expf(__fmul_rn(lp.w, 0.2f)));
    float hw = __fmul_rn(w, 0.5f), hh = __fmul_rn(h, 0.5f);
    float x1 = __fsub_rn(cx, hw), y1 = __fsub_rn(cy, hh);
    float x2 = __fadd_rn(cx, hw), y2 = __fadd_rn(cy, hh);
    bx[tid][0] = x1; bx[tid][1] = y1; bx[tid][2] = x2; bx[tid][3] = y2;
    vals[tid] = vv;
    sarea[tid] = __fmul_rn(__fsub_rn(x2, x1), __fsub_rn(y2, y1));  // ref area bits
    if (!(vv > 0.01f)) atomicMin(&s_nv, tid);
  }
  __syncthreads();
  const int n = s_nv;

  // ---- upper-triangle IoU mask matrix (only j > i consulted by the scan)
  if (tid < n) {
    float rx1 = bx[tid][0], ry1 = bx[tid][1], rx2 = bx[tid][2], ry2 = bx[tid][3];
    float ar = sarea[tid];
    u64 m0 = 0, m1 = 0, m2 = 0, m3 = 0;
    for (int j = tid + 1; j < n; ++j) {
      float jx1 = bx[j][0], jy1 = bx[j][1], jx2 = bx[j][2], jy2 = bx[j][3];
      float aj = sarea[j];
      float ww = fmaxf(__fsub_rn(fminf(rx2, jx2), fmaxf(rx1, jx1)), 0.0f);
      float hh = fmaxf(__fsub_rn(fminf(ry2, jy2), fmaxf(ry1, jy1)), 0.0f);
      float inter = __fmul_rn(ww, hh);
      float den = __fsub_rn(__fadd_rn(ar, aj), inter);
      float iou = __fdiv_rn(inter, den);   // NaN (0/0) -> comparison false
      if (iou > 0.45f) {
        u64 bit = 1ull << (j & 63);
        int w4 = j >> 6;
        if (w4 == 0) m0 |= bit; else if (w4 == 1) m1 |= bit;
        else if (w4 == 2) m2 |= bit; else m3 |= bit;
      }
    }
    msk[tid][0] = m0; msk[tid][1] = m1; msk[tid][2] = m2; msk[tid][3] = m3;
  }
  __syncthreads();

  // ---- scalar greedy scan on wave 0 only; broadcast keep-words via LDS
  if (tid < 64) {
    u64 remv0 = 0, remv1 = 0, remv2 = 0, remv3 = 0;
    u64 kp0 = 0, kp1 = 0, kp2 = 0, kp3 = 0;
    int i = 0;
#define SCAN_WORD(KW, RW)                                              \
    for (int bpos = 0; bpos < 64 && i < n; ++bpos, ++i) {              \
      if (!((RW >> bpos) & 1ull)) {                                    \
        KW |= 1ull << bpos;                                            \
        remv0 |= msk[i][0]; remv1 |= msk[i][1];                        \
        remv2 |= msk[i][2]; remv3 |= msk[i][3];                        \
      }                                                                \
    }
    SCAN_WORD(kp0, remv0)
    SCAN_WORD(kp1, remv1)
    SCAN_WORD(kp2, remv2)
    SCAN_WORD(kp3, remv3)
#undef SCAN_WORD
    if (tid == 0) { s_kp[0] = kp0; s_kp[1] = kp1; s_kp[2] = kp2; s_kp[3] = kp3; }
  }
  __syncthreads();
  const u64 kp0 = s_kp[0], kp1 = s_kp[1], kp2 = s_kp[2], kp3 = s_kp[3];

  for (int i = tid; i < TOPK * 5; i += 256) st[i] = 0.0f;   // st overlays hist/ckey (dead)
  __syncthreads();
  if (tid < TOPK) {
    int w4 = tid >> 6, bpos = tid & 63;
    u64 kw = (w4 == 0) ? kp0 : (w4 == 1) ? kp1 : (w4 == 2) ? kp2 : kp3;
    if ((kw >> bpos) & 1ull) {
      int pos = (int)__popcll(kw & ((1ull << bpos) - 1ull));
      if (w4 > 0) pos += (int)__popcll(kp0);
      if (w4 > 1) pos += (int)__popcll(kp1);
      if (w4 > 2) pos += (int)__popcll(kp2);
      st[pos * 5 + 0] = vals[tid];
      st[pos * 5 + 1] = bx[tid][0];
      st[pos * 5 + 2] = bx[tid][1];
      st[pos * 5 + 3] = bx[tid][2];
      st[pos * 5 + 4] = bx[tid][3];
    }
  }
  __syncthreads();
  float* op = out + (size_t)(b * NCLS + 1 + cm1) * (TOPK * 5);
  if (tid < TOPK * 5 / 4) ((float4*)op)[tid] = ((const float4*)st)[tid];
}

// ---------------- fused fallback (verified R13 kernel), used if ws tiny / odd P
__global__ __launch_bounds__(256) void fused_k(
    const float* __restrict__ loc, const float* __restrict__ conf,
    const float* __restrict__ priors, float* __restrict__ out, int B, int P) {
  __shared__ __align__(16) u32 sc[MAXP];
  __shared__ u64 ckey[CAND];
  __shared__ u32 hist[256];
  __shared__ int srt[TOPK];
  __shared__ float bx[TOPK][4];
  __shared__ float vals[TOPK];
  __shared__ __align__(16) float st[TOPK * 5];
  __shared__ u32 s_prefix;
  __shared__ int s_K, s_cnt, s_nv;
  __shared__ u64 s_kw[4];

  const int tid = threadIdx.x;
  const int task = blockIdx.x;
  const int b = task / (NCLS - 1), cm1 = task - b * (NCLS - 1);
  const int c = cm1 + 1;

  if (cm1 == 0) {
    float* bg = out + (size_t)b * (NCLS * TOPK * 5);
    for (int i = tid; i < TOPK * 5; i += 256) bg[i] = 0.0f;
  }
  for (int p = tid; p < P; p += 256) {
    float e[NCLS], mx, S;
    softmax_row(conf + ((size_t)b * P + p) * NCLS, e, mx, S);
    sc[p] = __float_as_uint(__fdiv_rn(e[c], S));
  }
  if (tid == 0) s_cnt = 0;
  __syncthreads();
  u32 prefix = 0; int K = TOPK;
  for (int pass = 0; pass < 4; ++pass) {
    int shift = 24 - 8 * pass;
    u32 known = (pass == 0) ? 0u : (0xFFFFFFFFu << (32 - 8 * pass));
    hist[tid] = 0;
    __syncthreads();
    for (int p = tid; p < P; p += 256) {
      u32 vv = sc[p];
      if ((vv & known) == prefix) atomicAdd(&hist[(vv >> shift) & 0xFFu], 1u);
    }
    __syncthreads();
    for (int off = 1; off < 256; off <<= 1) {
      u32 add = (tid + off < 256) ? hist[tid + off] : 0u;
      __syncthreads();
      hist[tid] += add;
      __syncthreads();
    }
    u32 ge = hist[tid];
    u32 gt = (tid == 255) ? 0u : hist[tid + 1];
    if (ge >= (u32)K && gt < (u32)K) { s_prefix = prefix | ((u32)tid << shift); s_K = K - (int)gt; }
    __syncthreads();
    prefix = s_prefix; K = s_K;
    __syncthreads();
  }
  const u32 T = prefix;
  for (int p = tid; p < P; p += 256) {
    u32 vv = sc[p];
    if (vv >= T) {
      int slot = atomicAdd(&s_cnt, 1);
      if (slot < CAND) ckey[slot] = ((u64)vv << 32) | (u64)(0xFFFFFFFFu - (u32)p);
    }
  }
  __syncthreads();
  int cnt = s_cnt; if (cnt > CAND) cnt = CAND;
  for (int i = tid; i < cnt; i += 256) {
    u64 k = ckey[i]; int r = 0;
    for (int j = 0; j < cnt; ++j) r += (ckey[j] > k) ? 1 : 0;
    if (r < TOPK) srt[r] = i;
  }
  if (tid == 0) s_nv = TOPK;
  __syncthreads();
  if (tid < TOPK) {
    u64 key = ckey[srt[tid]];
    float vv = __uint_as_float((u32)(key >> 32));
    int p = (int)(0xFFFFFFFFu - (u32)(key & 0xFFFFFFFFull));
    float4 lp = ((const float4*)loc)[(size_t)b * P + p];
    float4 pr = ((const float4*)priors)[p];
    float tx = __fmul_rn(__fmul_rn(lp.x, 0.1f), pr.z);
    float ty = __fmul_rn(__fmul_rn(lp.y, 0.1f), pr.w);
    float cx = __fadd_rn(pr.x, tx);
    float cy = __fadd_rn(pr.y, ty);
    float w = __fmul_rn(pr.z, expf(__fmul_rn(lp.z, 0.2f)));
    float h = __fmul_rn(pr.w, expf(__fmul_rn(lp.w, 0.2f)));
    float hw = __fmul_rn(w, 0.5f), hh = __fmul_rn(h, 0.5f);
    bx[tid][0] = __fsub_rn(cx, hw);
    bx[tid][1] = __fsub_rn(cy, hh);
    bx[tid][2] = __fadd_rn(cx, hw);
    bx[tid][3] = __fadd_rn(cy, hh);
    vals[tid] = vv;
    if (!(vv > 0.01f)) atomicMin(&s_nv, tid);
  }
  __syncthreads();
  if (tid < 64) {
    int lane = tid;
    float jx1[4], jy1[4], jx2[4], jy2[4], aj[4];
#pragma unroll
    for (int s = 0; s < 4; ++s) {
      int j = s * 64 + lane;
      if (j < TOPK) { jx1[s]=bx[j][0]; jy1[s]=bx[j][1]; jx2[s]=bx[j][2]; jy2[s]=bx[j][3]; }
      else { jx1[s]=0.f; jy1[s]=0.f; jx2[s]=0.f; jy2[s]=0.f; }
      aj[s] = __fmul_rn(__fsub_rn(jx2[s], jx1[s]), __fsub_rn(jy2[s], jy1[s]));
    }
    u32 keepn = 0;
    int n = s_nv;
    for (int i = 0; i < n; ++i) {
      float ix1 = bx[i][0], iy1 = bx[i][1], ix2 = bx[i][2], iy2 = bx[i][3];
      float ai = __fmul_rn(__fsub_rn(ix2, ix1), __fsub_rn(iy2, iy1));
      bool sup = false;
#pragma unroll
      for (int s = 0; s < 4; ++s) {
        float ww = fmaxf(__fsub_rn(fminf(ix2, jx2[s]), fmaxf(ix1, jx1[s])), 0.0f);
        float hh = fmaxf(__fsub_rn(fminf(iy2, jy2[s]), fmaxf(iy1, jy1[s])), 0.0f);
        float inter = __fmul_rn(ww, hh);
        float den = __fsub_rn(__fadd_rn(ai, aj[s]), inter);
        float iou = __fdiv_rn(inter, den);
        if (((keepn >> s) & 1u) && (iou > 0.45f)) sup = true;
      }
      if (!__any((int)sup)) { if (lane == (i & 63)) keepn |= 1u << (i >> 6); }
    }
    u64 w0 = __ballot((int)(keepn & 1u));
    u64 w1 = __ballot((int)((keepn >> 1) & 1u));
    u64 w2 = __ballot((int)((keepn >> 2) & 1u));
    u64 w3 = __ballot((int)((keepn >> 3) & 1u));
    if (lane == 0) { s_kw[0]=w0; s_kw[1]=w1; s_kw[2]=w2; s_kw[3]=w3; }
  }
  __syncthreads();
  for (int i = tid; i < TOPK * 5; i += 256) st[i] = 0.0f;
  __syncthreads();
  if (tid < TOPK) {
    int w = tid >> 6, bit = tid & 63;
    u64 kwv = s_kw[w];
    if ((kwv >> bit) & 1ull) {
      int pos = (int)__popcll(kwv & ((1ull << bit) - 1ull));
      for (int w2 = 0; w2 < w; ++w2) pos += (int)__popcll(s_kw[w2]);
      st[pos*5+0] = vals[tid];
      st[pos*5+1] = bx[tid][0];
      st[pos*5+2] = bx[tid][1];
      st[pos*5+3] = bx[tid][2];
      st[pos*5+4] = bx[tid][3];
    }
  }
  __syncthreads();
  float* op = out + (size_t)(b * NCLS + 1 + cm1) * (TOPK * 5);
  if (tid < TOPK * 5 / 4) ((float4*)op)[tid] = ((const float4*)st)[tid];
}

extern "C" void kernel_launch(void* const* d_in, const int* in_sizes, int n_in,
                              void* d_out, int out_size, void* d_ws, size_t ws_size,
                              hipStream_t stream) {
  const float* loc    = (const float*)d_in[0];
  const float* conf   = (const float*)d_in[1];
  const float* priors = (const float*)d_in[2];
  float* out = (float*)d_out;

  int P = in_sizes[2] / 4;              // 8732
  int B = in_sizes[0] / (P * 4);        // 128
  int tasks = B * (NCLS - 1);           // 2560
  int BP = B * P;

  size_t probB = (size_t)B * (NCLS - 1) * P * sizeof(float);    // ~89.4 MB

  if (ws_size >= probB && (P % 4) == 0 && P <= MAXP) {
    float* probs_t = (float*)d_ws;
    prep2_k<<<(BP + 255) / 256, 256, 0, stream>>>(conf, probs_t, B, P);
    fused4_k<<<tasks, 256, 0, stream>>>(loc, priors, probs_t, out, B, P);
  } else {
    fused_k<<<tasks, 256, 0, stream>>>(loc, conf, priors, out, B, P);
  }
}